// Round 1
// baseline (3640.716 us; speedup 1.0000x reference)
//
#include <hip/hip_runtime.h>

#define N_NODES 50000
#define N_EDGES 800000
#define D_IN 96
#define HID 64
#define D_OUT 16

// ---------------- degree / norm ----------------

__global__ void deg_kernel(const int* __restrict__ src, float* __restrict__ deg) {
    int e = blockIdx.x * blockDim.x + threadIdx.x;
    if (e < N_EDGES) atomicAdd(&deg[src[e]], 1.0f);
}

__global__ void dis_kernel(float* deg) {
    int i = blockIdx.x * blockDim.x + threadIdx.x;
    if (i < N_NODES) {
        float d = deg[i];
        deg[i] = d > 0.0f ? rsqrtf(d) : 0.0f;   // d is an exact integer count >= 1 when > 0
    }
}

__global__ void w_kernel(const int* __restrict__ src, const int* __restrict__ dst,
                         const float* __restrict__ dis, float* __restrict__ w) {
    int e = blockIdx.x * blockDim.x + threadIdx.x;
    if (e < N_EDGES) w[e] = -dis[src[e]] * dis[dst[e]];
}

// out = -in (vectorized), used to init Tx2 = -Tx0 before the scaled scatter
__global__ void negcopy_kernel(float* __restrict__ out, const float* __restrict__ in, long n4) {
    long t = blockIdx.x * (long)blockDim.x + threadIdx.x;
    if (t < n4) {
        float4 v = ((const float4*)in)[t];
        ((float4*)out)[t] = make_float4(-v.x, -v.y, -v.z, -v.w);
    }
}

// ---------------- sparse propagate: out[dst] += scale*w[e]*h[src] ----------------

template<int F>
__global__ void prop_kernel(const int* __restrict__ src, const int* __restrict__ dst,
                            const float* __restrict__ w, float scale,
                            const float* __restrict__ h, float* __restrict__ out) {
    const int TPE = F / 4;                       // threads per edge, float4 each
    const long total = (long)N_EDGES * TPE;
    const long stride = (long)gridDim.x * blockDim.x;
    for (long t = blockIdx.x * (long)blockDim.x + threadIdx.x; t < total; t += stride) {
        int e  = (int)(t / TPE);
        int fo = (int)(t % TPE) * 4;
        float we = scale * w[e];
        int s = src[e], d = dst[e];
        float4 hv = *(const float4*)(h + (long)s * F + fo);
        float* o = out + (long)d * F + fo;
        atomicAdd(o + 0, we * hv.x);
        atomicAdd(o + 1, we * hv.y);
        atomicAdd(o + 2, we * hv.z);
        atomicAdd(o + 3, we * hv.w);
    }
}

// ---------------- fused Cheb GEMM epilogues ----------------

// h = relu(Tx0@W[0] + Tx1@W[1] + Tx2@W[2] + b)   [N, HID], W: [3][D_IN][HID]
__global__ void gemm1_kernel(const float* __restrict__ Tx0, const float* __restrict__ Tx1,
                             const float* __restrict__ Tx2, const float* __restrict__ W,
                             const float* __restrict__ b, float* __restrict__ out) {
    int t = blockIdx.x * blockDim.x + threadIdx.x;
    int node = t / HID, o = t % HID;
    if (node >= N_NODES) return;
    const float* x0 = Tx0 + (long)node * D_IN;
    const float* x1 = Tx1 + (long)node * D_IN;
    const float* x2 = Tx2 + (long)node * D_IN;
    float acc = b[o];
    #pragma unroll 8
    for (int i = 0; i < D_IN; ++i) {
        acc = fmaf(x0[i], W[(0 * D_IN + i) * HID + o], acc);
        acc = fmaf(x1[i], W[(1 * D_IN + i) * HID + o], acc);
        acc = fmaf(x2[i], W[(2 * D_IN + i) * HID + o], acc);
    }
    out[t] = fmaxf(acc, 0.0f);
}

// y = Tx0@W[0] + Tx1@W[1] + Tx2@W[2] + b   [N, D_OUT], W: [3][HID][D_OUT]
__global__ void gemm2_kernel(const float* __restrict__ Tx0, const float* __restrict__ Tx1,
                             const float* __restrict__ Tx2, const float* __restrict__ W,
                             const float* __restrict__ b, float* __restrict__ out) {
    int t = blockIdx.x * blockDim.x + threadIdx.x;
    int node = t / D_OUT, o = t % D_OUT;
    if (node >= N_NODES) return;
    const float* x0 = Tx0 + (long)node * HID;
    const float* x1 = Tx1 + (long)node * HID;
    const float* x2 = Tx2 + (long)node * HID;
    float acc = b[o];
    #pragma unroll 8
    for (int i = 0; i < HID; ++i) {
        acc = fmaf(x0[i], W[(0 * HID + i) * D_OUT + o], acc);
        acc = fmaf(x1[i], W[(1 * HID + i) * D_OUT + o], acc);
        acc = fmaf(x2[i], W[(2 * HID + i) * D_OUT + o], acc);
    }
    out[t] = acc;
}

// ---------------- launch ----------------

extern "C" void kernel_launch(void* const* d_in, const int* in_sizes, int n_in,
                              void* d_out, int out_size, void* d_ws, size_t ws_size,
                              hipStream_t stream) {
    const float* x  = (const float*)d_in[0];
    const int*   ei = (const int*)d_in[1];
    const float* W1 = (const float*)d_in[2];
    const float* b1 = (const float*)d_in[3];
    const float* W2 = (const float*)d_in[4];
    const float* b2 = (const float*)d_in[5];
    const int* src = ei;
    const int* dst = ei + N_EDGES;

    float* ws   = (float*)d_ws;
    float* dis  = ws;                                // N        (deg then dis in-place)
    float* w    = dis  + N_NODES;                    // E
    float* Tx1a = w    + N_EDGES;                    // N*96
    float* Tx2a = Tx1a + (long)N_NODES * D_IN;       // N*96
    float* h    = Tx2a + (long)N_NODES * D_IN;       // N*64
    float* Tx1b = h    + (long)N_NODES * HID;        // N*64
    float* Tx2b = Tx1b + (long)N_NODES * HID;        // N*64
    // total: ~20.05M floats = 80.2 MB

    // --- norm weights ---
    hipMemsetAsync(dis, 0, N_NODES * sizeof(float), stream);
    deg_kernel<<<(N_EDGES + 255) / 256, 256, 0, stream>>>(src, dis);
    dis_kernel<<<(N_NODES + 255) / 256, 256, 0, stream>>>(dis);
    w_kernel<<<(N_EDGES + 255) / 256, 256, 0, stream>>>(src, dst, dis, w);

    // --- layer 1 (D_IN=96) ---
    hipMemsetAsync(Tx1a, 0, (size_t)N_NODES * D_IN * sizeof(float), stream);
    prop_kernel<D_IN><<<4096, 256, 0, stream>>>(src, dst, w, 1.0f, x, Tx1a);
    {
        long n4 = (long)N_NODES * D_IN / 4;
        negcopy_kernel<<<(int)((n4 + 255) / 256), 256, 0, stream>>>(Tx2a, x, n4);
    }
    prop_kernel<D_IN><<<4096, 256, 0, stream>>>(src, dst, w, 2.0f, Tx1a, Tx2a);
    gemm1_kernel<<<(N_NODES * HID + 255) / 256, 256, 0, stream>>>(x, Tx1a, Tx2a, W1, b1, h);

    // --- layer 2 (HID=64) ---
    hipMemsetAsync(Tx1b, 0, (size_t)N_NODES * HID * sizeof(float), stream);
    prop_kernel<HID><<<4096, 256, 0, stream>>>(src, dst, w, 1.0f, h, Tx1b);
    {
        long n4 = (long)N_NODES * HID / 4;
        negcopy_kernel<<<(int)((n4 + 255) / 256), 256, 0, stream>>>(Tx2b, h, n4);
    }
    prop_kernel<HID><<<4096, 256, 0, stream>>>(src, dst, w, 2.0f, Tx1b, Tx2b);
    gemm2_kernel<<<(N_NODES * D_OUT + 255) / 256, 256, 0, stream>>>(h, Tx1b, Tx2b, W2, b2, (float*)d_out);
}

// Round 2
// 644.206 us; speedup vs baseline: 5.6515x; 5.6515x over previous
//
#include <hip/hip_runtime.h>

#define N_NODES 50000
#define N_EDGES 800000
#define D_IN 96
#define HID 64
#define D_OUT 16

// ---------------- degree histograms ----------------

// deg_src as float (exact integer counts), deg_dst as int (for CSR)
__global__ void deg_kernel(const int* __restrict__ src, const int* __restrict__ dst,
                           float* __restrict__ deg_src, int* __restrict__ deg_dst) {
    int e = blockIdx.x * blockDim.x + threadIdx.x;
    if (e < N_EDGES) {
        atomicAdd(&deg_src[src[e]], 1.0f);
        atomicAdd(&deg_dst[dst[e]], 1);
    }
}

__global__ void dis_kernel(float* deg) {
    int i = blockIdx.x * blockDim.x + threadIdx.x;
    if (i < N_NODES) {
        float d = deg[i];
        deg[i] = d > 0.0f ? rsqrtf(d) : 0.0f;
    }
}

// ---------------- exclusive scan over deg_dst (single block) ----------------

__global__ void scan_kernel(const int* __restrict__ deg, int* __restrict__ row_ptr,
                            int* __restrict__ cursor) {
    __shared__ int sdata[1024];
    __shared__ int carry;
    if (threadIdx.x == 0) carry = 0;
    __syncthreads();
    for (int base = 0; base < N_NODES; base += 1024) {
        int i = base + (int)threadIdx.x;
        int v = (i < N_NODES) ? deg[i] : 0;
        sdata[threadIdx.x] = v;
        __syncthreads();
        for (int off = 1; off < 1024; off <<= 1) {
            int t = (threadIdx.x >= off) ? sdata[threadIdx.x - off] : 0;
            __syncthreads();
            sdata[threadIdx.x] += t;
            __syncthreads();
        }
        int incl = sdata[threadIdx.x];
        int excl = incl - v + carry;              // reads old carry
        if (i < N_NODES) { row_ptr[i] = excl; cursor[i] = excl; }
        __syncthreads();                          // all carry reads done
        if (threadIdx.x == 1023) carry += incl;   // chunk total
        __syncthreads();
    }
    if (threadIdx.x == 0) row_ptr[N_NODES] = carry;   // == N_EDGES
}

// ---------------- CSR scatter: group edges by dst, fold in weight ----------------

__global__ void scatter_kernel(const int* __restrict__ src, const int* __restrict__ dst,
                               const float* __restrict__ dis, int* __restrict__ cursor,
                               int* __restrict__ wsrc, float* __restrict__ wval) {
    int e = blockIdx.x * blockDim.x + threadIdx.x;
    if (e < N_EDGES) {
        int s = src[e], d = dst[e];
        int pos = atomicAdd(&cursor[d], 1);
        wsrc[pos] = s;
        wval[pos] = -dis[s] * dis[d];
    }
}

// ---------------- gather propagate ----------------
// CHEB2=false: out[d] = sum_e w*h[src]          (Tx1 = L x)
// CHEB2=true : out[d] = -tx0[d] + 2*sum w*h[src] (Tx2 = 2 L Tx1 - Tx0)

template<int F, bool CHEB2>
__global__ void gather_prop(const int* __restrict__ row_ptr, const int* __restrict__ wsrc,
                            const float* __restrict__ wval,
                            const float* __restrict__ h, const float* __restrict__ tx0,
                            float* __restrict__ out) {
    const int CPN = F / 4;   // float4 chunks per node
    int t = blockIdx.x * blockDim.x + threadIdx.x;
    int node = t / CPN, c = t % CPN;
    if (node >= N_NODES) return;
    int beg = row_ptr[node], end = row_ptr[node + 1];
    const float scale = CHEB2 ? 2.0f : 1.0f;
    float4 acc;
    if (CHEB2) {
        float4 t0 = *(const float4*)(tx0 + (long)node * F + c * 4);
        acc = make_float4(-t0.x, -t0.y, -t0.z, -t0.w);
    } else {
        acc = make_float4(0.f, 0.f, 0.f, 0.f);
    }
    #pragma unroll 2
    for (int e = beg; e < end; ++e) {
        float we = scale * wval[e];
        float4 hv = *(const float4*)(h + (long)wsrc[e] * F + c * 4);
        acc.x = fmaf(we, hv.x, acc.x);
        acc.y = fmaf(we, hv.y, acc.y);
        acc.z = fmaf(we, hv.z, acc.z);
        acc.w = fmaf(we, hv.w, acc.w);
    }
    *(float4*)(out + (long)node * F + c * 4) = acc;
}

// ---------------- fused Cheb GEMM epilogues ----------------

__global__ void gemm1_kernel(const float* __restrict__ Tx0, const float* __restrict__ Tx1,
                             const float* __restrict__ Tx2, const float* __restrict__ W,
                             const float* __restrict__ b, float* __restrict__ out) {
    int t = blockIdx.x * blockDim.x + threadIdx.x;
    int node = t / HID, o = t % HID;
    if (node >= N_NODES) return;
    const float* x0 = Tx0 + (long)node * D_IN;
    const float* x1 = Tx1 + (long)node * D_IN;
    const float* x2 = Tx2 + (long)node * D_IN;
    float acc = b[o];
    #pragma unroll 8
    for (int i = 0; i < D_IN; ++i) {
        acc = fmaf(x0[i], W[(0 * D_IN + i) * HID + o], acc);
        acc = fmaf(x1[i], W[(1 * D_IN + i) * HID + o], acc);
        acc = fmaf(x2[i], W[(2 * D_IN + i) * HID + o], acc);
    }
    out[t] = fmaxf(acc, 0.0f);
}

__global__ void gemm2_kernel(const float* __restrict__ Tx0, const float* __restrict__ Tx1,
                             const float* __restrict__ Tx2, const float* __restrict__ W,
                             const float* __restrict__ b, float* __restrict__ out) {
    int t = blockIdx.x * blockDim.x + threadIdx.x;
    int node = t / D_OUT, o = t % D_OUT;
    if (node >= N_NODES) return;
    const float* x0 = Tx0 + (long)node * HID;
    const float* x1 = Tx1 + (long)node * HID;
    const float* x2 = Tx2 + (long)node * HID;
    float acc = b[o];
    #pragma unroll 8
    for (int i = 0; i < HID; ++i) {
        acc = fmaf(x0[i], W[(0 * HID + i) * D_OUT + o], acc);
        acc = fmaf(x1[i], W[(1 * HID + i) * D_OUT + o], acc);
        acc = fmaf(x2[i], W[(2 * HID + i) * D_OUT + o], acc);
    }
    out[t] = acc;
}

// ---------------- launch ----------------

extern "C" void kernel_launch(void* const* d_in, const int* in_sizes, int n_in,
                              void* d_out, int out_size, void* d_ws, size_t ws_size,
                              hipStream_t stream) {
    const float* x  = (const float*)d_in[0];
    const int*   ei = (const int*)d_in[1];
    const float* W1 = (const float*)d_in[2];
    const float* b1 = (const float*)d_in[3];
    const float* W2 = (const float*)d_in[4];
    const float* b2 = (const float*)d_in[5];
    const int* src = ei;
    const int* dst = ei + N_EDGES;

    // workspace layout (16B-aligned sections)
    float* dis     = (float*)d_ws;                       // N   (deg_src -> dis in place)
    int*   deg_dst = (int*)(dis + N_NODES);              // N
    int*   row_ptr = deg_dst + N_NODES;                  // N+16 (padded for alignment)
    int*   cursor  = row_ptr + N_NODES + 16;             // N
    int*   wsrc    = cursor + N_NODES;                   // E
    float* wval    = (float*)(wsrc + N_EDGES);           // E
    float* Tx1a    = wval + N_EDGES;                     // N*96   (offset 1,800,016 elems: 16B aligned)
    float* Tx2a    = Tx1a + (long)N_NODES * D_IN;        // N*96
    float* h       = Tx2a + (long)N_NODES * D_IN;        // N*64
    float* Tx1b    = h    + (long)N_NODES * HID;         // N*64
    float* Tx2b    = Tx1b + (long)N_NODES * HID;         // N*64

    const int EB = (N_EDGES + 255) / 256;
    const int NB = (N_NODES + 255) / 256;

    // --- CSR build + norm weights ---
    hipMemsetAsync(dis, 0, N_NODES * sizeof(float), stream);
    hipMemsetAsync(deg_dst, 0, N_NODES * sizeof(int), stream);
    deg_kernel<<<EB, 256, 0, stream>>>(src, dst, dis, deg_dst);
    dis_kernel<<<NB, 256, 0, stream>>>(dis);
    scan_kernel<<<1, 1024, 0, stream>>>(deg_dst, row_ptr, cursor);
    scatter_kernel<<<EB, 256, 0, stream>>>(src, dst, dis, cursor, wsrc, wval);

    // --- layer 1 (F=96) ---
    {
        const int T = N_NODES * (D_IN / 4);
        gather_prop<D_IN, false><<<(T + 255) / 256, 256, 0, stream>>>(row_ptr, wsrc, wval, x, nullptr, Tx1a);
        gather_prop<D_IN, true ><<<(T + 255) / 256, 256, 0, stream>>>(row_ptr, wsrc, wval, Tx1a, x, Tx2a);
    }
    gemm1_kernel<<<(N_NODES * HID + 255) / 256, 256, 0, stream>>>(x, Tx1a, Tx2a, W1, b1, h);

    // --- layer 2 (F=64) ---
    {
        const int T = N_NODES * (HID / 4);
        gather_prop<HID, false><<<(T + 255) / 256, 256, 0, stream>>>(row_ptr, wsrc, wval, h, nullptr, Tx1b);
        gather_prop<HID, true ><<<(T + 255) / 256, 256, 0, stream>>>(row_ptr, wsrc, wval, Tx1b, h, Tx2b);
    }
    gemm2_kernel<<<(N_NODES * D_OUT + 255) / 256, 256, 0, stream>>>(h, Tx1b, Tx2b, W2, b2, (float*)d_out);
}

// Round 3
// 476.894 us; speedup vs baseline: 7.6342x; 1.3508x over previous
//
#include <hip/hip_runtime.h>

#define N_NODES 50000
#define N_EDGES 800000
#define D_IN 96
#define HID 64
#define D_OUT 16

// ---------------- degree histograms ----------------

__global__ void deg_kernel(const int* __restrict__ src, const int* __restrict__ dst,
                           float* __restrict__ deg_src, int* __restrict__ deg_dst) {
    int e = blockIdx.x * blockDim.x + threadIdx.x;
    if (e < N_EDGES) {
        atomicAdd(&deg_src[src[e]], 1.0f);
        atomicAdd(&deg_dst[dst[e]], 1);
    }
}

__global__ void dis_kernel(float* deg) {
    int i = blockIdx.x * blockDim.x + threadIdx.x;
    if (i < N_NODES) {
        float d = deg[i];
        deg[i] = d > 0.0f ? rsqrtf(d) : 0.0f;
    }
}

// ---------------- 3-phase exclusive scan: deg_dst -> row_ptr ----------------

#define SCAN_BLK 256
#define SCAN_GRID ((N_NODES + SCAN_BLK - 1) / SCAN_BLK)   // 196

__global__ void scanA_kernel(const int* __restrict__ deg, int* __restrict__ row_ptr,
                             int* __restrict__ btot) {
    __shared__ int wtot[4];
    int i = blockIdx.x * SCAN_BLK + threadIdx.x;
    int lane = threadIdx.x & 63, wid = threadIdx.x >> 6;
    int v = (i < N_NODES) ? deg[i] : 0;
    int incl = v;
    #pragma unroll
    for (int off = 1; off < 64; off <<= 1) {
        int t = __shfl_up(incl, off);
        if (lane >= off) incl += t;
    }
    if (lane == 63) wtot[wid] = incl;
    __syncthreads();
    int woff = 0;
    for (int w = 0; w < wid; ++w) woff += wtot[w];
    if (i < N_NODES) row_ptr[i] = woff + incl - v;
    if (threadIdx.x == SCAN_BLK - 1) btot[blockIdx.x] = woff + incl;
}

__global__ void scanB_kernel(const int* __restrict__ btot, int* __restrict__ boff) {
    __shared__ int s2[256];
    int t = threadIdx.x;
    int v = (t < SCAN_GRID) ? btot[t] : 0;
    s2[t] = v;
    __syncthreads();
    for (int off = 1; off < 256; off <<= 1) {
        int x = (t >= off) ? s2[t - off] : 0;
        __syncthreads();
        s2[t] += x;
        __syncthreads();
    }
    if (t < SCAN_GRID) boff[t] = s2[t] - v;
}

__global__ void scanC_kernel(int* __restrict__ row_ptr, int* __restrict__ cursor,
                             const int* __restrict__ boff) {
    int i = blockIdx.x * SCAN_BLK + threadIdx.x;
    if (i < N_NODES) {
        int v = row_ptr[i] + boff[blockIdx.x];
        row_ptr[i] = v;
        cursor[i] = v;
    }
    if (i == 0) row_ptr[N_NODES] = N_EDGES;
}

// ---------------- CSR scatter: group edges by dst, fold in weight ----------------

__global__ void scatter_kernel(const int* __restrict__ src, const int* __restrict__ dst,
                               const float* __restrict__ dis, int* __restrict__ cursor,
                               int* __restrict__ wsrc, float* __restrict__ wval) {
    int e = blockIdx.x * blockDim.x + threadIdx.x;
    if (e < N_EDGES) {
        int s = src[e], d = dst[e];
        int pos = atomicAdd(&cursor[d], 1);
        wsrc[pos] = s;
        wval[pos] = -dis[s] * dis[d];
    }
}

// ---------------- gather propagate with LDS edge staging ----------------
// CHEB2=false: out[d] = sum_e w*h[src]            (Tx1 = L x)
// CHEB2=true : out[d] = -tx0[d] + 2*sum w*h[src]  (Tx2 = 2 L Tx1 - Tx0)

template<int F, int NPB, int CAP, bool CHEB2>
__global__ __launch_bounds__(256)
void gather_prop(const int* __restrict__ row_ptr, const int* __restrict__ wsrc,
                 const float* __restrict__ wval, const float* __restrict__ h,
                 const float* __restrict__ tx0, float* __restrict__ out) {
    __shared__ int   s_src[CAP];
    __shared__ float s_w[CAP];
    __shared__ int   s_beg[NPB + 1];
    const int tid = threadIdx.x;
    const int node0 = blockIdx.x * NPB;
    if (tid <= NPB) {
        int n = node0 + tid;
        s_beg[tid] = row_ptr[n > N_NODES ? N_NODES : n];
    }
    __syncthreads();
    const int ebeg = s_beg[0];
    const int cnt = s_beg[NPB] - ebeg;
    const int stage = cnt < CAP ? cnt : CAP;
    for (int e = tid; e < stage; e += 256) {
        s_src[e] = wsrc[ebeg + e];
        s_w[e]   = wval[ebeg + e];
    }
    __syncthreads();
    const int CPN = F / 4;
    const int nl = tid / CPN;
    if (nl >= NPB) return;
    const int node = node0 + nl;
    if (node >= N_NODES) return;
    const int c4 = (tid % CPN) * 4;
    const float scale = CHEB2 ? 2.0f : 1.0f;
    float4 acc;
    if (CHEB2) {
        float4 t0 = *(const float4*)(tx0 + (long)node * F + c4);
        acc = make_float4(-t0.x, -t0.y, -t0.z, -t0.w);
    } else {
        acc = make_float4(0.f, 0.f, 0.f, 0.f);
    }
    const int beg = s_beg[nl] - ebeg;
    const int end = s_beg[nl + 1] - ebeg;
    const int mid = end < CAP ? end : CAP;
    #pragma unroll 2
    for (int e = beg; e < mid; ++e) {
        float we = scale * s_w[e];
        float4 hv = *(const float4*)(h + (long)s_src[e] * F + c4);
        acc.x = fmaf(we, hv.x, acc.x);
        acc.y = fmaf(we, hv.y, acc.y);
        acc.z = fmaf(we, hv.z, acc.z);
        acc.w = fmaf(we, hv.w, acc.w);
    }
    for (int e = (beg > CAP ? beg : CAP); e < end; ++e) {   // overflow fallback (rare)
        float we = scale * wval[ebeg + e];
        float4 hv = *(const float4*)(h + (long)wsrc[ebeg + e] * F + c4);
        acc.x = fmaf(we, hv.x, acc.x);
        acc.y = fmaf(we, hv.y, acc.y);
        acc.z = fmaf(we, hv.z, acc.z);
        acc.w = fmaf(we, hv.w, acc.w);
    }
    *(float4*)(out + (long)node * F + c4) = acc;
}

// ---------------- register-tiled wave GEMMs ----------------
// wave = 64 lanes = 64 output cols; 8 nodes per wave in registers.

#define G1_NPW 8
__global__ __launch_bounds__(256)
void gemm1_kernel(const float* __restrict__ Tx0, const float* __restrict__ Tx1,
                  const float* __restrict__ Tx2, const float* __restrict__ W,
                  const float* __restrict__ b, float* __restrict__ out) {
    const int lane = threadIdx.x & 63;
    const int wid = (blockIdx.x * blockDim.x + threadIdx.x) >> 6;
    const int node0 = wid * G1_NPW;
    if (node0 >= N_NODES) return;
    const int o = lane;
    float acc[G1_NPW];
    #pragma unroll
    for (int n = 0; n < G1_NPW; ++n) acc[n] = 0.0f;
    const float* Wo = W + o;
    for (int i = 0; i < D_IN; i += 4) {
        float wv[12];
        #pragma unroll
        for (int k = 0; k < 3; ++k)
            #pragma unroll
            for (int j = 0; j < 4; ++j)
                wv[k * 4 + j] = Wo[(k * D_IN + i + j) * HID];
        #pragma unroll
        for (int n = 0; n < G1_NPW; ++n) {
            long off = (long)(node0 + n) * D_IN + i;
            float4 x0 = *(const float4*)(Tx0 + off);
            float4 x1 = *(const float4*)(Tx1 + off);
            float4 x2 = *(const float4*)(Tx2 + off);
            float a = acc[n];
            a = fmaf(x0.x, wv[0], a);  a = fmaf(x0.y, wv[1], a);
            a = fmaf(x0.z, wv[2], a);  a = fmaf(x0.w, wv[3], a);
            a = fmaf(x1.x, wv[4], a);  a = fmaf(x1.y, wv[5], a);
            a = fmaf(x1.z, wv[6], a);  a = fmaf(x1.w, wv[7], a);
            a = fmaf(x2.x, wv[8], a);  a = fmaf(x2.y, wv[9], a);
            a = fmaf(x2.z, wv[10], a); a = fmaf(x2.w, wv[11], a);
            acc[n] = a;
        }
    }
    const float bias = b[o];
    #pragma unroll
    for (int n = 0; n < G1_NPW; ++n)
        out[(long)(node0 + n) * HID + o] = fmaxf(acc[n] + bias, 0.0f);
}

// gemm2: lane = (sub,o) = (lane>>4, lane&15); 4*G2_NPW nodes per wave
#define G2_NPW 8
__global__ __launch_bounds__(256)
void gemm2_kernel(const float* __restrict__ Tx0, const float* __restrict__ Tx1,
                  const float* __restrict__ Tx2, const float* __restrict__ W,
                  const float* __restrict__ b, float* __restrict__ out) {
    const int lane = threadIdx.x & 63;
    const int sub = lane >> 4;
    const int o = lane & 15;
    const int wid = (blockIdx.x * blockDim.x + threadIdx.x) >> 6;
    const int node0 = wid * 4 * G2_NPW;
    if (node0 >= N_NODES) return;
    float acc[G2_NPW];
    #pragma unroll
    for (int g = 0; g < G2_NPW; ++g) acc[g] = 0.0f;
    const float* Wo = W + o;
    for (int i = 0; i < HID; i += 4) {
        float wv[12];
        #pragma unroll
        for (int k = 0; k < 3; ++k)
            #pragma unroll
            for (int j = 0; j < 4; ++j)
                wv[k * 4 + j] = Wo[(k * HID + i + j) * D_OUT];
        #pragma unroll
        for (int g = 0; g < G2_NPW; ++g) {
            int node = node0 + g * 4 + sub;
            if (node < N_NODES) {
                long off = (long)node * HID + i;
                float4 x0 = *(const float4*)(Tx0 + off);
                float4 x1 = *(const float4*)(Tx1 + off);
                float4 x2 = *(const float4*)(Tx2 + off);
                float a = acc[g];
                a = fmaf(x0.x, wv[0], a);  a = fmaf(x0.y, wv[1], a);
                a = fmaf(x0.z, wv[2], a);  a = fmaf(x0.w, wv[3], a);
                a = fmaf(x1.x, wv[4], a);  a = fmaf(x1.y, wv[5], a);
                a = fmaf(x1.z, wv[6], a);  a = fmaf(x1.w, wv[7], a);
                a = fmaf(x2.x, wv[8], a);  a = fmaf(x2.y, wv[9], a);
                a = fmaf(x2.z, wv[10], a); a = fmaf(x2.w, wv[11], a);
                acc[g] = a;
            }
        }
    }
    const float bias = b[o];
    #pragma unroll
    for (int g = 0; g < G2_NPW; ++g) {
        int node = node0 + g * 4 + sub;
        if (node < N_NODES) out[(long)node * D_OUT + o] = acc[g] + bias;
    }
}

// ---------------- launch ----------------

extern "C" void kernel_launch(void* const* d_in, const int* in_sizes, int n_in,
                              void* d_out, int out_size, void* d_ws, size_t ws_size,
                              hipStream_t stream) {
    const float* x  = (const float*)d_in[0];
    const int*   ei = (const int*)d_in[1];
    const float* W1 = (const float*)d_in[2];
    const float* b1 = (const float*)d_in[3];
    const float* W2 = (const float*)d_in[4];
    const float* b2 = (const float*)d_in[5];
    const int* src = ei;
    const int* dst = ei + N_EDGES;

    // workspace layout (keep float4 alignment for the big arrays)
    float* dis     = (float*)d_ws;                       // N
    int*   deg_dst = (int*)(dis + N_NODES);              // N
    int*   row_ptr = deg_dst + N_NODES;                  // N+1 (+pad)
    int*   cursor  = row_ptr + N_NODES + 16;             // N
    int*   btot    = cursor + N_NODES;                   // 256
    int*   boff    = btot + 256;                         // 256
    int*   wsrc    = boff + 256;                         // E
    float* wval    = (float*)(wsrc + N_EDGES);           // E
    float* Tx1a    = wval + N_EDGES;                     // N*96
    float* Tx2a    = Tx1a + (long)N_NODES * D_IN;        // N*96
    float* h       = Tx2a + (long)N_NODES * D_IN;        // N*64
    float* Tx1b    = h    + (long)N_NODES * HID;         // N*64
    float* Tx2b    = Tx1b + (long)N_NODES * HID;         // N*64

    const int EB = (N_EDGES + 255) / 256;
    const int NB = (N_NODES + 255) / 256;

    // --- CSR build + norm weights ---
    hipMemsetAsync(dis, 0, N_NODES * sizeof(float), stream);
    hipMemsetAsync(deg_dst, 0, N_NODES * sizeof(int), stream);
    deg_kernel<<<EB, 256, 0, stream>>>(src, dst, dis, deg_dst);
    dis_kernel<<<NB, 256, 0, stream>>>(dis);
    scanA_kernel<<<SCAN_GRID, SCAN_BLK, 0, stream>>>(deg_dst, row_ptr, btot);
    scanB_kernel<<<1, 256, 0, stream>>>(btot, boff);
    scanC_kernel<<<SCAN_GRID, SCAN_BLK, 0, stream>>>(row_ptr, cursor, boff);
    scatter_kernel<<<EB, 256, 0, stream>>>(src, dst, dis, cursor, wsrc, wval);

    // --- layer 1 (F=96): NPB=10 -> 5000 blocks exactly ---
    gather_prop<D_IN, 10, 384, false><<<N_NODES / 10, 256, 0, stream>>>(row_ptr, wsrc, wval, x, nullptr, Tx1a);
    gather_prop<D_IN, 10, 384, true ><<<N_NODES / 10, 256, 0, stream>>>(row_ptr, wsrc, wval, Tx1a, x, Tx2a);
    gemm1_kernel<<<(N_NODES / G1_NPW + 3) / 4, 256, 0, stream>>>(x, Tx1a, Tx2a, W1, b1, h);

    // --- layer 2 (F=64): NPB=16 -> 3125 blocks exactly ---
    gather_prop<HID, 16, 640, false><<<N_NODES / 16, 256, 0, stream>>>(row_ptr, wsrc, wval, h, nullptr, Tx1b);
    gather_prop<HID, 16, 640, true ><<<N_NODES / 16, 256, 0, stream>>>(row_ptr, wsrc, wval, Tx1b, h, Tx2b);
    {
        int waves = (N_NODES + 4 * G2_NPW - 1) / (4 * G2_NPW);
        gemm2_kernel<<<(waves + 3) / 4, 256, 0, stream>>>(h, Tx1b, Tx2b, W2, b2, (float*)d_out);
    }
}

// Round 4
// 278.884 us; speedup vs baseline: 13.0546x; 1.7100x over previous
//
#include <hip/hip_runtime.h>

#define N_NODES 50000
#define N_EDGES 800000
#define D_IN 96
#define HID 64
#define D_OUT 16

typedef unsigned short u16;
typedef unsigned int u32;
typedef __attribute__((ext_vector_type(4))) float f32x4;
typedef __attribute__((ext_vector_type(8))) short bf16x8;

__device__ inline float bflo(u32 v) { union { u32 i; float f; } u; u.i = v << 16; return u.f; }
__device__ inline float bfhi(u32 v) { union { u32 i; float f; } u; u.i = v & 0xffff0000u; return u.f; }
__device__ inline u16 f2bf(float f) {            // RTNE, no NaN handling needed for this data
    union { float f; u32 i; } u; u.f = f;
    return (u16)((u.i + 0x7fffu + ((u.i >> 16) & 1u)) >> 16);
}
__device__ inline u32 pack2(float lo, float hi) {
    return (u32)f2bf(lo) | ((u32)f2bf(hi) << 16);
}

// ---------------- degree histograms / norm ----------------

__global__ void deg_kernel(const int* __restrict__ src, const int* __restrict__ dst,
                           float* __restrict__ deg_src, int* __restrict__ deg_dst) {
    int e = blockIdx.x * blockDim.x + threadIdx.x;
    if (e < N_EDGES) {
        atomicAdd(&deg_src[src[e]], 1.0f);
        atomicAdd(&deg_dst[dst[e]], 1);
    }
}

__global__ void dis_kernel(float* deg) {
    int i = blockIdx.x * blockDim.x + threadIdx.x;
    if (i < N_NODES) {
        float d = deg[i];
        deg[i] = d > 0.0f ? rsqrtf(d) : 0.0f;
    }
}

// ---------------- 3-phase exclusive scan: deg_dst -> row_ptr ----------------

#define SCAN_BLK 256
#define SCAN_GRID ((N_NODES + SCAN_BLK - 1) / SCAN_BLK)   // 196

__global__ void scanA_kernel(const int* __restrict__ deg, int* __restrict__ row_ptr,
                             int* __restrict__ btot) {
    __shared__ int wtot[4];
    int i = blockIdx.x * SCAN_BLK + threadIdx.x;
    int lane = threadIdx.x & 63, wid = threadIdx.x >> 6;
    int v = (i < N_NODES) ? deg[i] : 0;
    int incl = v;
    #pragma unroll
    for (int off = 1; off < 64; off <<= 1) {
        int t = __shfl_up(incl, off);
        if (lane >= off) incl += t;
    }
    if (lane == 63) wtot[wid] = incl;
    __syncthreads();
    int woff = 0;
    for (int w = 0; w < wid; ++w) woff += wtot[w];
    if (i < N_NODES) row_ptr[i] = woff + incl - v;
    if (threadIdx.x == SCAN_BLK - 1) btot[blockIdx.x] = woff + incl;
}

__global__ void scanB_kernel(const int* __restrict__ btot, int* __restrict__ boff) {
    __shared__ int s2[256];
    int t = threadIdx.x;
    int v = (t < SCAN_GRID) ? btot[t] : 0;
    s2[t] = v;
    __syncthreads();
    for (int off = 1; off < 256; off <<= 1) {
        int x = (t >= off) ? s2[t - off] : 0;
        __syncthreads();
        s2[t] += x;
        __syncthreads();
    }
    if (t < SCAN_GRID) boff[t] = s2[t] - v;
}

__global__ void scanC_kernel(int* __restrict__ row_ptr, int* __restrict__ cursor,
                             const int* __restrict__ boff) {
    int i = blockIdx.x * SCAN_BLK + threadIdx.x;
    if (i < N_NODES) {
        int v = row_ptr[i] + boff[blockIdx.x];
        row_ptr[i] = v;
        cursor[i] = v;
    }
    if (i == 0) row_ptr[N_NODES] = N_EDGES;
}

// ---------------- CSR scatter ----------------

__global__ void scatter_kernel(const int* __restrict__ src, const int* __restrict__ dst,
                               const float* __restrict__ dis, int* __restrict__ cursor,
                               int* __restrict__ wsrc, float* __restrict__ wval) {
    int e = blockIdx.x * blockDim.x + threadIdx.x;
    if (e < N_EDGES) {
        int s = src[e], d = dst[e];
        int pos = atomicAdd(&cursor[d], 1);
        wsrc[pos] = s;
        wval[pos] = -dis[s] * dis[d];
    }
}

// ---------------- f32 -> bf16 convert (8 elems/thread) ----------------

__global__ void cvt_kernel(const float* __restrict__ in, u16* __restrict__ out, int n8) {
    int t = blockIdx.x * blockDim.x + threadIdx.x;
    if (t >= n8) return;
    const float4* p = (const float4*)(in + (long)t * 8);
    float4 a = p[0], b = p[1];
    uint4 r;
    r.x = pack2(a.x, a.y); r.y = pack2(a.z, a.w);
    r.z = pack2(b.x, b.y); r.w = pack2(b.z, b.w);
    *(uint4*)(out + (long)t * 8) = r;
}

// ---------------- pack W into MFMA B-fragment order (bf16) ----------------
// P[((kt*4+sub)*NC + c)*8 + j] = B[kt*32+sub*8+j][c],  B[i][kc*OUTW+o] = W[kc][i][o]

__global__ void packB_kernel(const float* __restrict__ W, u16* __restrict__ P,
                             int K, int NC, int OUTW, int total) {
    int t = blockIdx.x * blockDim.x + threadIdx.x;
    if (t >= total) return;
    int j = t & 7;
    int rest = t >> 3;
    int c = rest % NC;
    int i = (rest / NC) * 8 + j;
    int kc = c / OUTW, o = c % OUTW;
    P[t] = f2bf(W[((long)kc * K + i) * OUTW + o]);
}

// ---------------- MFMA GEMM: Z = A[N,K] @ B[K,NC], bf16 in, bf16 out ----------
// store col c=ct*16+r16 at Z + (ct/CPK)*CBS + node*LDZ + (ct%CPK)*16 + r16

template<int K, int NC, int LDZ, int CPK, long CBS>
__global__ __launch_bounds__(256)
void gemm_mfma(const u16* __restrict__ A, const u16* __restrict__ P, u16* __restrict__ Z) {
    constexpr int KT = K / 32;
    constexpr int TOT = KT * 4 * NC * 8;
    __shared__ u16 sP[TOT];
    for (int idx = threadIdx.x * 8; idx < TOT; idx += 2048)
        *(uint4*)&sP[idx] = *(const uint4*)&P[idx];
    __syncthreads();
    const int lane = threadIdx.x & 63;
    const int tile = blockIdx.x * 4 + (threadIdx.x >> 6);
    if (tile * 16 >= N_NODES) return;
    const int node0 = tile * 16;
    const int sub = lane >> 4, r16 = lane & 15;
    bf16x8 a[KT];
    const u16* arow = A + (long)(node0 + r16) * K + sub * 8;
    #pragma unroll
    for (int kt = 0; kt < KT; ++kt)
        a[kt] = *(const bf16x8*)(arow + kt * 32);
    #pragma unroll
    for (int ct = 0; ct < NC / 16; ++ct) {
        f32x4 acc = {0.f, 0.f, 0.f, 0.f};
        #pragma unroll
        for (int kt = 0; kt < KT; ++kt) {
            bf16x8 b = *(const bf16x8*)&sP[((kt * 4 + sub) * NC + ct * 16 + r16) * 8];
            acc = __builtin_amdgcn_mfma_f32_16x16x32_bf16(a[kt], b, acc, 0, 0, 0);
        }
        u16* zp = Z + (long)(ct / CPK) * CBS + (long)(node0 + sub * 4) * LDZ + (ct % CPK) * 16 + r16;
        #pragma unroll
        for (int r = 0; r < 4; ++r)
            zp[(long)r * LDZ] = f2bf(acc[r]);
    }
}

// ---------------- bf16 gather propagate: out[d] = sum_e w*h[src] ----------------

__device__ inline void accum8(float (&acc)[8], float we, uint4 q) {
    acc[0] = fmaf(we, bflo(q.x), acc[0]);
    acc[1] = fmaf(we, bfhi(q.x), acc[1]);
    acc[2] = fmaf(we, bflo(q.y), acc[2]);
    acc[3] = fmaf(we, bfhi(q.y), acc[3]);
    acc[4] = fmaf(we, bflo(q.z), acc[4]);
    acc[5] = fmaf(we, bfhi(q.z), acc[5]);
    acc[6] = fmaf(we, bflo(q.w), acc[6]);
    acc[7] = fmaf(we, bfhi(q.w), acc[7]);
}

template<int F, int NPB, int CAP>
__global__ __launch_bounds__(256)
void gather_prop_bf(const int* __restrict__ row_ptr, const int* __restrict__ wsrc,
                    const float* __restrict__ wval,
                    const u16* __restrict__ h, int ldh,
                    u16* __restrict__ out, int ldo) {
    __shared__ int   s_src[CAP];
    __shared__ float s_w[CAP];
    __shared__ int   s_beg[NPB + 1];
    const int tid = threadIdx.x;
    const int node0 = blockIdx.x * NPB;
    if (tid <= NPB) {
        int n = node0 + tid;
        s_beg[tid] = row_ptr[n > N_NODES ? N_NODES : n];
    }
    __syncthreads();
    const int ebeg = s_beg[0];
    const int cnt = s_beg[NPB] - ebeg;
    const int stage = cnt < CAP ? cnt : CAP;
    for (int e = tid; e < stage; e += 256) {
        s_src[e] = wsrc[ebeg + e];
        s_w[e]   = wval[ebeg + e];
    }
    __syncthreads();
    const int CPN = F / 8;
    const int nl = tid / CPN;
    const int node = node0 + nl;
    if (nl >= NPB || node >= N_NODES) return;
    const int c8 = (tid % CPN) * 8;
    float acc[8];
    #pragma unroll
    for (int j = 0; j < 8; ++j) acc[j] = 0.0f;
    const int beg = s_beg[nl] - ebeg;
    const int end = s_beg[nl + 1] - ebeg;
    const int mid = end < stage ? end : stage;
    for (int e = beg; e < mid; ++e) {
        const float we = s_w[e];
        const uint4 q = *(const uint4*)(h + (long)s_src[e] * ldh + c8);
        accum8(acc, we, q);
    }
    for (int e = (beg > stage ? beg : stage); e < end; ++e) {   // overflow fallback (rare)
        const float we = wval[ebeg + e];
        const uint4 q = *(const uint4*)(h + (long)wsrc[ebeg + e] * ldh + c8);
        accum8(acc, we, q);
    }
    uint4 r;
    r.x = pack2(acc[0], acc[1]); r.y = pack2(acc[2], acc[3]);
    r.z = pack2(acc[4], acc[5]); r.w = pack2(acc[6], acc[7]);
    *(uint4*)(out + (long)node * ldo + c8) = r;
}

// ---------------- combine layer 1: h = relu(Z0 - Z2 + P1 + 2*P2 + b) ----------------

__global__ __launch_bounds__(256)
void combine1_kernel(const u16* __restrict__ Z, const u16* __restrict__ P1,
                     const u16* __restrict__ P2, const float* __restrict__ b,
                     u16* __restrict__ h) {
    int t = blockIdx.x * blockDim.x + threadIdx.x;
    if (t >= N_NODES * 8) return;              // 8 chunks of 8 per node (HID=64)
    int node = t >> 3, c8 = (t & 7) * 8;
    long o64 = (long)node * HID + c8;
    uint4 z0 = *(const uint4*)(Z + o64);
    uint4 z2 = *(const uint4*)(Z + (long)2 * N_NODES * HID + o64);
    uint4 p1 = *(const uint4*)(P1 + o64);
    uint4 p2 = *(const uint4*)(P2 + o64);
    const float* bb = b + c8;
    float v0 = bflo(z0.x) - bflo(z2.x) + bflo(p1.x) + 2.f * bflo(p2.x) + bb[0];
    float v1 = bfhi(z0.x) - bfhi(z2.x) + bfhi(p1.x) + 2.f * bfhi(p2.x) + bb[1];
    float v2 = bflo(z0.y) - bflo(z2.y) + bflo(p1.y) + 2.f * bflo(p2.y) + bb[2];
    float v3 = bfhi(z0.y) - bfhi(z2.y) + bfhi(p1.y) + 2.f * bfhi(p2.y) + bb[3];
    float v4 = bflo(z0.z) - bflo(z2.z) + bflo(p1.z) + 2.f * bflo(p2.z) + bb[4];
    float v5 = bfhi(z0.z) - bfhi(z2.z) + bfhi(p1.z) + 2.f * bfhi(p2.z) + bb[5];
    float v6 = bflo(z0.w) - bflo(z2.w) + bflo(p1.w) + 2.f * bflo(p2.w) + bb[6];
    float v7 = bfhi(z0.w) - bfhi(z2.w) + bfhi(p1.w) + 2.f * bfhi(p2.w) + bb[7];
    uint4 r;
    r.x = pack2(fmaxf(v0, 0.f), fmaxf(v1, 0.f));
    r.y = pack2(fmaxf(v2, 0.f), fmaxf(v3, 0.f));
    r.z = pack2(fmaxf(v4, 0.f), fmaxf(v5, 0.f));
    r.w = pack2(fmaxf(v6, 0.f), fmaxf(v7, 0.f));
    *(uint4*)(h + o64) = r;
}

// ---------------- final: out = Z'0 - Z'2 + P1' + 2*P2' + b2 (f32) ----------------

__global__ __launch_bounds__(256)
void final_kernel(const u16* __restrict__ Zp, const u16* __restrict__ P1,
                  const u16* __restrict__ P2, const float* __restrict__ b,
                  float* __restrict__ out) {
    int t = blockIdx.x * blockDim.x + threadIdx.x;
    if (t >= N_NODES * 2) return;              // 2 chunks of 8 per node (D_OUT=16)
    int node = t >> 1, c8 = (t & 1) * 8;
    long o16 = (long)node * D_OUT + c8;
    uint4 z0 = *(const uint4*)(Zp + o16);
    uint4 z2 = *(const uint4*)(Zp + (long)2 * N_NODES * D_OUT + o16);
    uint4 p1 = *(const uint4*)(P1 + o16);
    uint4 p2 = *(const uint4*)(P2 + o16);
    const float* bb = b + c8;
    float4 r0, r1;
    r0.x = bflo(z0.x) - bflo(z2.x) + bflo(p1.x) + 2.f * bflo(p2.x) + bb[0];
    r0.y = bfhi(z0.x) - bfhi(z2.x) + bfhi(p1.x) + 2.f * bfhi(p2.x) + bb[1];
    r0.z = bflo(z0.y) - bflo(z2.y) + bflo(p1.y) + 2.f * bflo(p2.y) + bb[2];
    r0.w = bfhi(z0.y) - bfhi(z2.y) + bfhi(p1.y) + 2.f * bfhi(p2.y) + bb[3];
    r1.x = bflo(z0.z) - bflo(z2.z) + bflo(p1.z) + 2.f * bflo(p2.z) + bb[4];
    r1.y = bfhi(z0.z) - bfhi(z2.z) + bfhi(p1.z) + 2.f * bfhi(p2.z) + bb[5];
    r1.z = bflo(z0.w) - bflo(z2.w) + bflo(p1.w) + 2.f * bflo(p2.w) + bb[6];
    r1.w = bfhi(z0.w) - bfhi(z2.w) + bfhi(p1.w) + 2.f * bfhi(p2.w) + bb[7];
    *(float4*)(out + o16) = r0;
    *(float4*)(out + o16 + 4) = r1;
}

// ---------------- launch ----------------

extern "C" void kernel_launch(void* const* d_in, const int* in_sizes, int n_in,
                              void* d_out, int out_size, void* d_ws, size_t ws_size,
                              hipStream_t stream) {
    const float* x  = (const float*)d_in[0];
    const int*   ei = (const int*)d_in[1];
    const float* W1 = (const float*)d_in[2];
    const float* b1 = (const float*)d_in[3];
    const float* W2 = (const float*)d_in[4];
    const float* b2 = (const float*)d_in[5];
    const int* src = ei;
    const int* dst = ei + N_EDGES;

    // workspace layout (all sections 16B-aligned)
    float* dis     = (float*)d_ws;                           // N
    int*   deg_dst = (int*)(dis + N_NODES);                  // N
    int*   row_ptr = deg_dst + N_NODES;                      // N+1 (+pad)
    int*   cursor  = row_ptr + N_NODES + 16;                 // N
    int*   btot    = cursor + N_NODES;                       // 256
    int*   boff    = btot + 256;                             // 256
    int*   wsrc    = boff + 256;                             // E
    float* wval    = (float*)(wsrc + N_EDGES);               // E
    u16*   xb      = (u16*)(wval + N_EDGES);                 // N*96  bf16 x
    u16*   Pb1     = xb + (long)N_NODES * D_IN;              // 18432
    u16*   Pb2     = Pb1 + 18432;                            // 3072
    u16*   Z       = Pb2 + 3072;                             // [3][N][64]
    u16*   P1      = Z   + (long)3 * N_NODES * HID;          // N*64
    u16*   Q       = P1  + (long)N_NODES * HID;              // N*64
    u16*   P2      = Q   + (long)N_NODES * HID;              // N*64
    u16*   hb      = P2  + (long)N_NODES * HID;              // N*64
    u16*   Zp      = hb  + (long)N_NODES * HID;              // [3][N][16]
    u16*   P1p     = Zp  + (long)3 * N_NODES * D_OUT;        // N*16
    u16*   Qp      = P1p + (long)N_NODES * D_OUT;            // N*16
    u16*   P2p     = Qp  + (long)N_NODES * D_OUT;            // N*16

    const int EB = (N_EDGES + 255) / 256;
    const int NB = (N_NODES + 255) / 256;

    // --- CSR build + norm weights ---
    hipMemsetAsync(dis, 0, N_NODES * sizeof(float), stream);
    hipMemsetAsync(deg_dst, 0, N_NODES * sizeof(int), stream);
    deg_kernel<<<EB, 256, 0, stream>>>(src, dst, dis, deg_dst);
    dis_kernel<<<NB, 256, 0, stream>>>(dis);
    scanA_kernel<<<SCAN_GRID, SCAN_BLK, 0, stream>>>(deg_dst, row_ptr, btot);
    scanB_kernel<<<1, 256, 0, stream>>>(btot, boff);
    scanC_kernel<<<SCAN_GRID, SCAN_BLK, 0, stream>>>(row_ptr, cursor, boff);
    scatter_kernel<<<EB, 256, 0, stream>>>(src, dst, dis, cursor, wsrc, wval);

    // --- convert + pack ---
    cvt_kernel<<<(N_NODES * D_IN / 8 + 255) / 256, 256, 0, stream>>>(x, xb, N_NODES * D_IN / 8);
    packB_kernel<<<(3 * D_IN * HID + 255) / 256, 256, 0, stream>>>(W1, Pb1, D_IN, 3 * HID, HID, 3 * D_IN * HID);
    packB_kernel<<<(3 * HID * D_OUT + 255) / 256, 256, 0, stream>>>(W2, Pb2, HID, 3 * D_OUT, D_OUT, 3 * HID * D_OUT);

    // --- layer 1: Z = x @ W1 (MFMA), then props in 64-dim space ---
    const int GB = (N_NODES / 16 + 3) / 4;   // 782
    gemm_mfma<D_IN, 3 * HID, HID, 4, (long)N_NODES * HID><<<GB, 256, 0, stream>>>(xb, Pb1, Z);
    gather_prop_bf<HID, 32, 1024><<<(N_NODES + 31) / 32, 256, 0, stream>>>(
        row_ptr, wsrc, wval, Z + (long)N_NODES * HID, HID, P1, HID);            // P1 = L Z1
    gather_prop_bf<HID, 32, 1024><<<(N_NODES + 31) / 32, 256, 0, stream>>>(
        row_ptr, wsrc, wval, Z + (long)2 * N_NODES * HID, HID, Q, HID);         // Q = L Z2
    gather_prop_bf<HID, 32, 1024><<<(N_NODES + 31) / 32, 256, 0, stream>>>(
        row_ptr, wsrc, wval, Q, HID, P2, HID);                                  // P2 = L Q
    combine1_kernel<<<(N_NODES * 8 + 255) / 256, 256, 0, stream>>>(Z, P1, P2, b1, hb);

    // --- layer 2: Z' = h @ W2 (MFMA), props in 16-dim space ---
    gemm_mfma<HID, 3 * D_OUT, D_OUT, 1, (long)N_NODES * D_OUT><<<GB, 256, 0, stream>>>(hb, Pb2, Zp);
    gather_prop_bf<D_OUT, 128, 3072><<<(N_NODES + 127) / 128, 256, 0, stream>>>(
        row_ptr, wsrc, wval, Zp + (long)N_NODES * D_OUT, D_OUT, P1p, D_OUT);    // P1' = L Z'1
    gather_prop_bf<D_OUT, 128, 3072><<<(N_NODES + 127) / 128, 256, 0, stream>>>(
        row_ptr, wsrc, wval, Zp + (long)2 * N_NODES * D_OUT, D_OUT, Qp, D_OUT); // Q' = L Z'2
    gather_prop_bf<D_OUT, 128, 3072><<<(N_NODES + 127) / 128, 256, 0, stream>>>(
        row_ptr, wsrc, wval, Qp, D_OUT, P2p, D_OUT);                            // P2' = L Q'
    final_kernel<<<(N_NODES * 2 + 255) / 256, 256, 0, stream>>>(Zp, P1p, P2p, b2, (float*)d_out);
}

// Round 5
// 194.593 us; speedup vs baseline: 18.7094x; 1.4332x over previous
//
#include <hip/hip_runtime.h>

#define N_NODES 50000
#define N_EDGES 800000
#define D_IN 96
#define HID 64
#define D_OUT 16

#define EPB 2048                                   // edges per block (passes A/C)
#define NBLK_E ((N_EDGES + EPB - 1) / EPB)         // 391
#define BSHIFT 7                                   // 128 nodes per bucket
#define NBKT ((N_NODES + 127) / 128)               // 391
#define DCAP 2560                                  // Ddst LDS edge staging cap

typedef unsigned short u16;
typedef unsigned int u32;
typedef __attribute__((ext_vector_type(4))) float f32x4;
typedef __attribute__((ext_vector_type(8))) short bf16x8;

__device__ inline float bflo(u32 v) { union { u32 i; float f; } u; u.i = v << 16; return u.f; }
__device__ inline float bfhi(u32 v) { union { u32 i; float f; } u; u.i = v & 0xffff0000u; return u.f; }
__device__ inline u16 f2bf(float f) {              // RTNE
    union { float f; u32 i; } u; u.f = f;
    return (u16)((u.i + 0x7fffu + ((u.i >> 16) & 1u)) >> 16);
}
__device__ inline u32 pack2(float lo, float hi) {
    return (u32)f2bf(lo) | ((u32)f2bf(hi) << 16);
}

// ============ CSR build: two-level counting sort, zero global atomics ============

// Pass A: per-block coarse-bucket histograms for src and dst.
__global__ __launch_bounds__(256)
void passA(const int* __restrict__ src, const int* __restrict__ dst,
           int* __restrict__ blk_cnt_src, int* __restrict__ blk_cnt_dst) {
    __shared__ int hs[NBKT], hd[NBKT];
    const int t = threadIdx.x, blk = blockIdx.x;
    for (int i = t; i < NBKT; i += 256) { hs[i] = 0; hd[i] = 0; }
    __syncthreads();
    const int e0 = blk * EPB;
    const int e1 = (e0 + EPB < N_EDGES) ? e0 + EPB : N_EDGES;
    for (int e = e0 + t; e < e1; e += 256) {
        atomicAdd(&hs[src[e] >> BSHIFT], 1);
        atomicAdd(&hd[dst[e] >> BSHIFT], 1);
    }
    __syncthreads();
    for (int b = t; b < NBKT; b += 256) {
        blk_cnt_src[b * NBLK_E + blk] = hs[b];
        blk_cnt_dst[b * NBLK_E + blk] = hd[b];
    }
}

// Pass B: per-bucket exclusive scan over the block dimension (in place), emit totals.
__global__ __launch_bounds__(64)
void passB(int* __restrict__ blk_cnt_src, int* __restrict__ blk_cnt_dst,
           int* __restrict__ tot_src, int* __restrict__ tot_dst) {
    const int b = blockIdx.x;
    int* cnt; int* tot;
    if (b < NBKT) { cnt = blk_cnt_dst + b * NBLK_E;          tot = tot_dst + b; }
    else          { cnt = blk_cnt_src + (b - NBKT) * NBLK_E; tot = tot_src + (b - NBKT); }
    const int lane = threadIdx.x;
    int carry = 0;
    for (int base = 0; base < NBLK_E; base += 64) {
        int i = base + lane;
        int v = (i < NBLK_E) ? cnt[i] : 0;
        int incl = v;
        #pragma unroll
        for (int off = 1; off < 64; off <<= 1) {
            int x = __shfl_up(incl, off);
            if (lane >= off) incl += x;
        }
        if (i < NBLK_E) cnt[i] = carry + incl - v;
        carry += __shfl(incl, 63);
    }
    if (lane == 0) *tot = carry;
}

// Pass B2: scan bucket totals -> bucket bases (dst and src); row_ptr[N]=E.
__global__ __launch_bounds__(256)
void passB2(const int* __restrict__ tot_src, const int* __restrict__ tot_dst,
            int* __restrict__ base_src, int* __restrict__ base_dst, int* __restrict__ row_ptr) {
    __shared__ int s[512];
    const int t = threadIdx.x;
    for (int pass = 0; pass < 2; ++pass) {
        const int* tot = pass ? tot_src : tot_dst;
        int* bas = pass ? base_src : base_dst;
        s[t]       = (t < NBKT) ? tot[t] : 0;
        s[t + 256] = (t + 256 < NBKT) ? tot[t + 256] : 0;
        __syncthreads();
        for (int off = 1; off < 512; off <<= 1) {
            int a1 = (t >= off) ? s[t - off] : 0;
            int a2 = (t + 256 >= off) ? s[t + 256 - off] : 0;
            __syncthreads();
            s[t] += a1; s[t + 256] += a2;
            __syncthreads();
        }
        if (t == 0) bas[0] = 0;
        if (t < NBKT) bas[t + 1] = s[t];
        if (t + 256 < NBKT) bas[t + 257] = s[t + 256];
        __syncthreads();
    }
    if (t == 0) row_ptr[N_NODES] = N_EDGES;
}

// Pass C: scatter edges into coarse-bucket-sorted arrays via LDS cursors.
__global__ __launch_bounds__(256)
void passC(const int* __restrict__ src, const int* __restrict__ dst,
           const int* __restrict__ blk_off_src, const int* __restrict__ blk_off_dst,
           const int* __restrict__ base_src, const int* __restrict__ base_dst,
           int* __restrict__ sorted_srconly, int* __restrict__ sorted_dst,
           int* __restrict__ sorted_srcpair) {
    __shared__ int cs[NBKT], cd[NBKT];
    const int t = threadIdx.x, blk = blockIdx.x;
    for (int b = t; b < NBKT; b += 256) {
        cs[b] = base_src[b] + blk_off_src[b * NBLK_E + blk];
        cd[b] = base_dst[b] + blk_off_dst[b * NBLK_E + blk];
    }
    __syncthreads();
    const int e0 = blk * EPB;
    const int e1 = (e0 + EPB < N_EDGES) ? e0 + EPB : N_EDGES;
    for (int e = e0 + t; e < e1; e += 256) {
        int sv = src[e], dv = dst[e];
        int ps = atomicAdd(&cs[sv >> BSHIFT], 1);
        sorted_srconly[ps] = sv;
        int pd = atomicAdd(&cd[dv >> BSHIFT], 1);
        sorted_dst[pd] = dv;
        sorted_srcpair[pd] = sv;
    }
}

// Pass Dsrc: per-bucket histogram of bucket-sorted src -> dis = rsqrt(deg).
__global__ __launch_bounds__(256)
void passDsrc(const int* __restrict__ base_src, const int* __restrict__ sorted_srconly,
              float* __restrict__ dis) {
    __shared__ int hist[128];
    const int b = blockIdx.x, t = threadIdx.x;
    if (t < 128) hist[t] = 0;
    __syncthreads();
    const int eb = base_src[b], ee = base_src[b + 1];
    for (int i = eb + t; i < ee; i += 256)
        atomicAdd(&hist[sorted_srconly[i] & 127], 1);
    __syncthreads();
    const int node = (b << BSHIFT) + t;
    if (t < 128 && node < N_NODES) {
        int c = hist[t];
        dis[node] = c > 0 ? rsqrtf((float)c) : 0.0f;
    }
}

// Pass Ddst: per-bucket fine CSR: row_ptr, node-grouped wsrc, wval = -dis[s]*dis[d].
__global__ __launch_bounds__(256)
void passDdst(const int* __restrict__ base_dst, const int* __restrict__ sorted_dst,
              const int* __restrict__ sorted_srcpair, const float* __restrict__ dis,
              int* __restrict__ row_ptr, int* __restrict__ wsrc, float* __restrict__ wval) {
    __shared__ int s_d[DCAP];
    __shared__ int s_s[DCAP];
    __shared__ int hist[128];
    __shared__ int cur[128];
    __shared__ float s_dis[128];
    const int b = blockIdx.x, t = threadIdx.x;
    if (t < 128) {
        hist[t] = 0;
        int node = (b << BSHIFT) + t;
        s_dis[t] = (node < N_NODES) ? dis[node] : 0.0f;
    }
    __syncthreads();
    const int eb = base_dst[b], ee = base_dst[b + 1];
    const int cnt = ee - eb;
    const int stage = cnt < DCAP ? cnt : DCAP;
    for (int i = t; i < stage; i += 256) {
        int d = sorted_dst[eb + i] & 127;
        s_d[i] = d;
        s_s[i] = sorted_srcpair[eb + i];
        atomicAdd(&hist[d], 1);
    }
    for (int i = stage + t; i < cnt; i += 256)          // overflow (shouldn't happen)
        atomicAdd(&hist[sorted_dst[eb + i] & 127], 1);
    __syncthreads();
    if (t < 64) {                                       // scan 128 counters in wave 0
        int v0 = hist[2 * t], v1 = hist[2 * t + 1];
        int p = v0 + v1;
        int incl = p;
        #pragma unroll
        for (int off = 1; off < 64; off <<= 1) {
            int x = __shfl_up(incl, off);
            if (t >= off) incl += x;
        }
        int excl = incl - p;
        cur[2 * t] = excl;
        cur[2 * t + 1] = excl + v0;
        int node = (b << BSHIFT) + 2 * t;
        if (node < N_NODES) row_ptr[node] = eb + excl;
        if (node + 1 < N_NODES) row_ptr[node + 1] = eb + excl + v0;
    }
    __syncthreads();
    for (int i = t; i < stage; i += 256) {
        int ln = s_d[i], sv = s_s[i];
        int slot = atomicAdd(&cur[ln], 1);
        wsrc[eb + slot] = sv;
        wval[eb + slot] = -dis[sv] * s_dis[ln];
    }
    for (int i = stage + t; i < cnt; i += 256) {        // overflow fallback
        int ln = sorted_dst[eb + i] & 127, sv = sorted_srcpair[eb + i];
        int slot = atomicAdd(&cur[ln], 1);
        wsrc[eb + slot] = sv;
        wval[eb + slot] = -dis[sv] * s_dis[ln];
    }
}

// ============ weight pack (both layers, MFMA B-fragment order) ============
// P[((kt*4+sub)*NC + c)*8 + j] = B[kt*32+sub*8+j][c], where B[i][kc*OUTW+o] = W[kc][i][o]

__global__ void packB_both(const float* __restrict__ W1, const float* __restrict__ W2,
                           u16* __restrict__ Pb1, u16* __restrict__ Pb2) {
    int t = blockIdx.x * blockDim.x + threadIdx.x;
    if (t < 3 * D_IN * HID) {                    // 18432: K=96, NC=192, OUTW=64
        int j = t & 7, rest = t >> 3;
        int c = rest % 192, i = (rest / 192) * 8 + j;
        int kc = c / 64, o = c % 64;
        Pb1[t] = f2bf(W1[((long)kc * D_IN + i) * HID + o]);
    } else if (t < 3 * D_IN * HID + 3 * HID * D_OUT) {
        int t2 = t - 3 * D_IN * HID;             // 3072: K=64, NC=48, OUTW=16
        int j = t2 & 7, rest = t2 >> 3;
        int c = rest % 48, i = (rest / 48) * 8 + j;
        int kc = c / 16, o = c % 16;
        Pb2[t2] = f2bf(W2[((long)kc * HID + i) * D_OUT + o]);
    }
}

// ============ MFMA GEMM: Z[N,NC] = A[N,K] @ B[K,NC] (interleaved k-blocks) ============

template<int K, int NC, bool AF32>
__global__ __launch_bounds__(256)
void gemm_mfma(const void* __restrict__ Av, const u16* __restrict__ P, u16* __restrict__ Z) {
    constexpr int KT = K / 32;
    constexpr int TOT = KT * 4 * NC * 8;
    __shared__ u16 sP[TOT];
    for (int idx = threadIdx.x * 8; idx < TOT; idx += 2048)
        *(uint4*)&sP[idx] = *(const uint4*)&P[idx];
    __syncthreads();
    const int lane = threadIdx.x & 63;
    const int tile = blockIdx.x * 4 + (threadIdx.x >> 6);
    if (tile * 16 >= N_NODES) return;
    const int node0 = tile * 16;
    const int sub = lane >> 4, r16 = lane & 15;
    bf16x8 a[KT];
    if (AF32) {
        const float* ar = (const float*)Av + (long)(node0 + r16) * K + sub * 8;
        #pragma unroll
        for (int kt = 0; kt < KT; ++kt) {
            float4 a0 = *(const float4*)(ar + kt * 32);
            float4 a1 = *(const float4*)(ar + kt * 32 + 4);
            union { bf16x8 v; uint4 q; } u;
            u.q.x = pack2(a0.x, a0.y); u.q.y = pack2(a0.z, a0.w);
            u.q.z = pack2(a1.x, a1.y); u.q.w = pack2(a1.z, a1.w);
            a[kt] = u.v;
        }
    } else {
        const u16* ar = (const u16*)Av + (long)(node0 + r16) * K + sub * 8;
        #pragma unroll
        for (int kt = 0; kt < KT; ++kt)
            a[kt] = *(const bf16x8*)(ar + kt * 32);
    }
    #pragma unroll
    for (int ct = 0; ct < NC / 16; ++ct) {
        f32x4 acc = {0.f, 0.f, 0.f, 0.f};
        #pragma unroll
        for (int kt = 0; kt < KT; ++kt) {
            bf16x8 bfr = *(const bf16x8*)&sP[((kt * 4 + sub) * NC + ct * 16 + r16) * 8];
            acc = __builtin_amdgcn_mfma_f32_16x16x32_bf16(a[kt], bfr, acc, 0, 0, 0);
        }
        u16* zp = Z + (long)(node0 + sub * 4) * NC + ct * 16 + r16;
        #pragma unroll
        for (int r = 0; r < 4; ++r)
            zp[(long)r * NC] = f2bf(acc[r]);
    }
}

// ============ bf16 gather propagate: out[d] = sum_e w*h[src] ============

__device__ inline void accum8(float (&acc)[8], float we, uint4 q) {
    acc[0] = fmaf(we, bflo(q.x), acc[0]);
    acc[1] = fmaf(we, bfhi(q.x), acc[1]);
    acc[2] = fmaf(we, bflo(q.y), acc[2]);
    acc[3] = fmaf(we, bfhi(q.y), acc[3]);
    acc[4] = fmaf(we, bflo(q.z), acc[4]);
    acc[5] = fmaf(we, bfhi(q.z), acc[5]);
    acc[6] = fmaf(we, bflo(q.w), acc[6]);
    acc[7] = fmaf(we, bfhi(q.w), acc[7]);
}

template<int F, int NPB, int CAP>
__global__ __launch_bounds__(256)
void gather_prop_bf(const int* __restrict__ row_ptr, const int* __restrict__ wsrc,
                    const float* __restrict__ wval,
                    const u16* __restrict__ h, int ldh,
                    u16* __restrict__ out, int ldo) {
    __shared__ int   s_src[CAP];
    __shared__ float s_w[CAP];
    __shared__ int   s_beg[NPB + 1];
    const int tid = threadIdx.x;
    const int node0 = blockIdx.x * NPB;
    if (tid <= NPB) {
        int n = node0 + tid;
        s_beg[tid] = row_ptr[n > N_NODES ? N_NODES : n];
    }
    __syncthreads();
    const int ebeg = s_beg[0];
    const int cnt = s_beg[NPB] - ebeg;
    const int stage = cnt < CAP ? cnt : CAP;
    for (int e = tid; e < stage; e += 256) {
        s_src[e] = wsrc[ebeg + e];
        s_w[e]   = wval[ebeg + e];
    }
    __syncthreads();
    const int CPN = F / 8;
    const int nl = tid / CPN;
    const int node = node0 + nl;
    if (nl >= NPB || node >= N_NODES) return;
    const int c8 = (tid % CPN) * 8;
    float acc[8];
    #pragma unroll
    for (int j = 0; j < 8; ++j) acc[j] = 0.0f;
    const int beg = s_beg[nl] - ebeg;
    const int end = s_beg[nl + 1] - ebeg;
    const int mid = end < stage ? end : stage;
    for (int e = beg; e < mid; ++e) {
        const float we = s_w[e];
        const uint4 q = *(const uint4*)(h + (long)s_src[e] * ldh + c8);
        accum8(acc, we, q);
    }
    for (int e = (beg > stage ? beg : stage); e < end; ++e) {   // overflow fallback
        const float we = wval[ebeg + e];
        const uint4 q = *(const uint4*)(h + (long)wsrc[ebeg + e] * ldh + c8);
        accum8(acc, we, q);
    }
    uint4 r;
    r.x = pack2(acc[0], acc[1]); r.y = pack2(acc[2], acc[3]);
    r.z = pack2(acc[4], acc[5]); r.w = pack2(acc[6], acc[7]);
    *(uint4*)(out + (long)node * ldo + c8) = r;
}

// ============ combine layer 1: h = relu(Z0 - Z2 + P1 + 2*P2 + b1) ============
// Z: [N,192] = [Z0|Z1|Z2]; P1 in P1Q[N,128] cols 0..63; P2: [N,64]

__global__ __launch_bounds__(256)
void combine1_kernel(const u16* __restrict__ Z, const u16* __restrict__ P1Q,
                     const u16* __restrict__ P2, const float* __restrict__ b,
                     u16* __restrict__ h) {
    int t = blockIdx.x * blockDim.x + threadIdx.x;
    if (t >= N_NODES * 8) return;
    int node = t >> 3, c8 = (t & 7) * 8;
    uint4 z0 = *(const uint4*)(Z + (long)node * 192 + c8);
    uint4 z2 = *(const uint4*)(Z + (long)node * 192 + 128 + c8);
    uint4 p1 = *(const uint4*)(P1Q + (long)node * 128 + c8);
    uint4 p2 = *(const uint4*)(P2 + (long)node * 64 + c8);
    const float* bb = b + c8;
    float v0 = bflo(z0.x) - bflo(z2.x) + bflo(p1.x) + 2.f * bflo(p2.x) + bb[0];
    float v1 = bfhi(z0.x) - bfhi(z2.x) + bfhi(p1.x) + 2.f * bfhi(p2.x) + bb[1];
    float v2 = bflo(z0.y) - bflo(z2.y) + bflo(p1.y) + 2.f * bflo(p2.y) + bb[2];
    float v3 = bfhi(z0.y) - bfhi(z2.y) + bfhi(p1.y) + 2.f * bfhi(p2.y) + bb[3];
    float v4 = bflo(z0.z) - bflo(z2.z) + bflo(p1.z) + 2.f * bflo(p2.z) + bb[4];
    float v5 = bfhi(z0.z) - bfhi(z2.z) + bfhi(p1.z) + 2.f * bfhi(p2.z) + bb[5];
    float v6 = bflo(z0.w) - bflo(z2.w) + bflo(p1.w) + 2.f * bflo(p2.w) + bb[6];
    float v7 = bfhi(z0.w) - bfhi(z2.w) + bfhi(p1.w) + 2.f * bfhi(p2.w) + bb[7];
    uint4 r;
    r.x = pack2(fmaxf(v0, 0.f), fmaxf(v1, 0.f));
    r.y = pack2(fmaxf(v2, 0.f), fmaxf(v3, 0.f));
    r.z = pack2(fmaxf(v4, 0.f), fmaxf(v5, 0.f));
    r.w = pack2(fmaxf(v6, 0.f), fmaxf(v7, 0.f));
    *(uint4*)(h + (long)node * 64 + c8) = r;
}

// ============ final: out = Z'0 - Z'2 + P1' + 2*P2' + b2 (f32 out) ============
// Zp: [N,48] = [Z'0|Z'1|Z'2]; P1' in P1Qp[N,32] cols 0..15; P2p: [N,16]

__global__ __launch_bounds__(256)
void final_kernel(const u16* __restrict__ Zp, const u16* __restrict__ P1Qp,
                  const u16* __restrict__ P2p, const float* __restrict__ b,
                  float* __restrict__ out) {
    int t = blockIdx.x * blockDim.x + threadIdx.x;
    if (t >= N_NODES * 2) return;
    int node = t >> 1, c8 = (t & 1) * 8;
    uint4 z0 = *(const uint4*)(Zp + (long)node * 48 + c8);
    uint4 z2 = *(const uint4*)(Zp + (long)node * 48 + 32 + c8);
    uint4 p1 = *(const uint4*)(P1Qp + (long)node * 32 + c8);
    uint4 p2 = *(const uint4*)(P2p + (long)node * 16 + c8);
    const float* bb = b + c8;
    float4 r0, r1;
    r0.x = bflo(z0.x) - bflo(z2.x) + bflo(p1.x) + 2.f * bflo(p2.x) + bb[0];
    r0.y = bfhi(z0.x) - bfhi(z2.x) + bfhi(p1.x) + 2.f * bfhi(p2.x) + bb[1];
    r0.z = bflo(z0.y) - bflo(z2.y) + bflo(p1.y) + 2.f * bflo(p2.y) + bb[2];
    r0.w = bfhi(z0.y) - bfhi(z2.y) + bfhi(p1.y) + 2.f * bfhi(p2.y) + bb[3];
    r1.x = bflo(z0.z) - bflo(z2.z) + bflo(p1.z) + 2.f * bflo(p2.z) + bb[4];
    r1.y = bfhi(z0.z) - bfhi(z2.z) + bfhi(p1.z) + 2.f * bfhi(p2.z) + bb[5];
    r1.z = bflo(z0.w) - bflo(z2.w) + bflo(p1.w) + 2.f * bflo(p2.w) + bb[6];
    r1.w = bfhi(z0.w) - bfhi(z2.w) + bfhi(p1.w) + 2.f * bfhi(p2.w) + bb[7];
    long o16 = (long)node * D_OUT + c8;
    *(float4*)(out + o16) = r0;
    *(float4*)(out + o16 + 4) = r1;
}

// ============ launch ============

extern "C" void kernel_launch(void* const* d_in, const int* in_sizes, int n_in,
                              void* d_out, int out_size, void* d_ws, size_t ws_size,
                              hipStream_t stream) {
    const float* x  = (const float*)d_in[0];
    const int*   ei = (const int*)d_in[1];
    const float* W1 = (const float*)d_in[2];
    const float* b1 = (const float*)d_in[3];
    const float* W2 = (const float*)d_in[4];
    const float* b2 = (const float*)d_in[5];
    const int* src = ei;
    const int* dst = ei + N_EDGES;

    // ---- workspace (all sections 16B-aligned) ----
    float* dis          = (float*)d_ws;                      // 50000
    int*   row_ptr      = (int*)(dis + N_NODES);             // 50016
    int*   blk_cnt_src  = row_ptr + 50016;                   // 152896 (391*391 pad)
    int*   blk_cnt_dst  = blk_cnt_src + 152896;              // 152896
    int*   tot_src      = blk_cnt_dst + 152896;              // 512
    int*   tot_dst      = tot_src + 512;                     // 512
    int*   base_src     = tot_dst + 512;                     // 512
    int*   base_dst     = base_src + 512;                    // 512
    int*   sorted_dst   = base_dst + 512;                    // E
    int*   sorted_srcp  = sorted_dst + N_EDGES;              // E
    int*   wsrc         = sorted_srcp + N_EDGES;             // E (aliases sorted_srconly)
    float* wval         = (float*)(wsrc + N_EDGES);          // E
    u16*   Pb1          = (u16*)(wval + N_EDGES);            // 18432
    u16*   Pb2          = Pb1 + 18432;                       // 3072
    u16*   Z            = Pb2 + 3072;                        // N*192
    u16*   P1Q          = Z + (long)N_NODES * 192;           // N*128
    u16*   P2           = P1Q + (long)N_NODES * 128;         // N*64
    u16*   hb           = P2 + (long)N_NODES * 64;           // N*64
    u16*   Zp           = hb + (long)N_NODES * 64;           // N*48
    u16*   P1Qp         = Zp + (long)N_NODES * 48;           // N*32
    u16*   P2p          = P1Qp + (long)N_NODES * 32;         // N*16
    int*   sorted_srconly = wsrc;                            // reuse: consumed before wsrc written

    // ---- CSR build (no global atomics) ----
    passA<<<NBLK_E, 256, 0, stream>>>(src, dst, blk_cnt_src, blk_cnt_dst);
    passB<<<2 * NBKT, 64, 0, stream>>>(blk_cnt_src, blk_cnt_dst, tot_src, tot_dst);
    passB2<<<1, 256, 0, stream>>>(tot_src, tot_dst, base_src, base_dst, row_ptr);
    passC<<<NBLK_E, 256, 0, stream>>>(src, dst, blk_cnt_src, blk_cnt_dst, base_src, base_dst,
                                      sorted_srconly, sorted_dst, sorted_srcp);
    passDsrc<<<NBKT, 256, 0, stream>>>(base_src, sorted_srconly, dis);
    passDdst<<<NBKT, 256, 0, stream>>>(base_dst, sorted_dst, sorted_srcp, dis,
                                       row_ptr, wsrc, wval);

    // ---- weights ----
    packB_both<<<(3 * D_IN * HID + 3 * HID * D_OUT + 255) / 256, 256, 0, stream>>>(W1, W2, Pb1, Pb2);

    // ---- layer 1: Z = x @ W1 (f32->bf16 in-register), props, combine ----
    const int GB = (N_NODES / 16 + 3) / 4;   // 782
    gemm_mfma<D_IN, 192, true><<<GB, 256, 0, stream>>>(x, Pb1, Z);
    gather_prop_bf<128, 16, 640><<<N_NODES / 16, 256, 0, stream>>>(
        row_ptr, wsrc, wval, Z + 64, 192, P1Q, 128);                  // [P1|Q] = L [Z1|Z2]
    gather_prop_bf<64, 32, 1024><<<(N_NODES + 31) / 32, 256, 0, stream>>>(
        row_ptr, wsrc, wval, P1Q + 64, 128, P2, 64);                  // P2 = L Q
    combine1_kernel<<<(N_NODES * 8 + 255) / 256, 256, 0, stream>>>(Z, P1Q, P2, b1, hb);

    // ---- layer 2: Zp = h @ W2, props, final ----
    gemm_mfma<HID, 48, false><<<GB, 256, 0, stream>>>(hb, Pb2, Zp);
    gather_prop_bf<32, 64, 1536><<<(N_NODES + 63) / 64, 256, 0, stream>>>(
        row_ptr, wsrc, wval, Zp + 16, 48, P1Qp, 32);                  // [P1'|Q'] = L [Z'1|Z'2]
    gather_prop_bf<16, 128, 3072><<<(N_NODES + 127) / 128, 256, 0, stream>>>(
        row_ptr, wsrc, wval, P1Qp + 16, 32, P2p, 16);                 // P2' = L Q'
    final_kernel<<<(N_NODES * 2 + 255) / 256, 256, 0, stream>>>(Zp, P1Qp, P2p, b2, (float*)d_out);
}

// Round 6
// 146.415 us; speedup vs baseline: 24.8657x; 1.3290x over previous
//
#include <hip/hip_runtime.h>

#define N_NODES 50000
#define N_EDGES 800000
#define D_IN 96
#define HID 64
#define D_OUT 16

#define EPB 2048                                   // edges per block (passes A/C)
#define NBLK_E ((N_EDGES + EPB - 1) / EPB)         // 391
#define BSHIFT 7                                   // 128 nodes per bucket
#define NBKT ((N_NODES + 127) / 128)               // 391
#define DCAP 2560                                  // Ddst LDS edge staging cap

typedef unsigned short u16;
typedef unsigned int u32;
typedef __attribute__((ext_vector_type(4))) float f32x4;
typedef __attribute__((ext_vector_type(8))) short bf16x8;

__device__ inline float bflo(u32 v) { union { u32 i; float f; } u; u.i = v << 16; return u.f; }
__device__ inline float bfhi(u32 v) { union { u32 i; float f; } u; u.i = v & 0xffff0000u; return u.f; }
__device__ inline u16 f2bf(float f) {              // RTNE
    union { float f; u32 i; } u; u.f = f;
    return (u16)((u.i + 0x7fffu + ((u.i >> 16) & 1u)) >> 16);
}
__device__ inline u32 pack2(float lo, float hi) {
    return (u32)f2bf(lo) | ((u32)f2bf(hi) << 16);
}

// ============ CSR build: two-level counting sort, zero global atomics ============

__global__ __launch_bounds__(256)
void passA(const int* __restrict__ src, const int* __restrict__ dst,
           int* __restrict__ blk_cnt_src, int* __restrict__ blk_cnt_dst) {
    __shared__ int hs[NBKT], hd[NBKT];
    const int t = threadIdx.x, blk = blockIdx.x;
    for (int i = t; i < NBKT; i += 256) { hs[i] = 0; hd[i] = 0; }
    __syncthreads();
    const int e0 = blk * EPB;
    const int e1 = (e0 + EPB < N_EDGES) ? e0 + EPB : N_EDGES;
    for (int e = e0 + t; e < e1; e += 256) {
        atomicAdd(&hs[src[e] >> BSHIFT], 1);
        atomicAdd(&hd[dst[e] >> BSHIFT], 1);
    }
    __syncthreads();
    for (int b = t; b < NBKT; b += 256) {
        blk_cnt_src[b * NBLK_E + blk] = hs[b];
        blk_cnt_dst[b * NBLK_E + blk] = hd[b];
    }
}

__global__ __launch_bounds__(64)
void passB(int* __restrict__ blk_cnt_src, int* __restrict__ blk_cnt_dst,
           int* __restrict__ tot_src, int* __restrict__ tot_dst) {
    const int b = blockIdx.x;
    int* cnt; int* tot;
    if (b < NBKT) { cnt = blk_cnt_dst + b * NBLK_E;          tot = tot_dst + b; }
    else          { cnt = blk_cnt_src + (b - NBKT) * NBLK_E; tot = tot_src + (b - NBKT); }
    const int lane = threadIdx.x;
    int carry = 0;
    for (int base = 0; base < NBLK_E; base += 64) {
        int i = base + lane;
        int v = (i < NBLK_E) ? cnt[i] : 0;
        int incl = v;
        #pragma unroll
        for (int off = 1; off < 64; off <<= 1) {
            int x = __shfl_up(incl, off);
            if (lane >= off) incl += x;
        }
        if (i < NBLK_E) cnt[i] = carry + incl - v;
        carry += __shfl(incl, 63);
    }
    if (lane == 0) *tot = carry;
}

__global__ __launch_bounds__(256)
void passB2(const int* __restrict__ tot_src, const int* __restrict__ tot_dst,
            int* __restrict__ base_src, int* __restrict__ base_dst, int* __restrict__ row_ptr) {
    __shared__ int s[512];
    const int t = threadIdx.x;
    for (int pass = 0; pass < 2; ++pass) {
        const int* tot = pass ? tot_src : tot_dst;
        int* bas = pass ? base_src : base_dst;
        s[t]       = (t < NBKT) ? tot[t] : 0;
        s[t + 256] = (t + 256 < NBKT) ? tot[t + 256] : 0;
        __syncthreads();
        for (int off = 1; off < 512; off <<= 1) {
            int a1 = (t >= off) ? s[t - off] : 0;
            int a2 = (t + 256 >= off) ? s[t + 256 - off] : 0;
            __syncthreads();
            s[t] += a1; s[t + 256] += a2;
            __syncthreads();
        }
        if (t == 0) bas[0] = 0;
        if (t < NBKT) bas[t + 1] = s[t];
        if (t + 256 < NBKT) bas[t + 257] = s[t + 256];
        __syncthreads();
    }
    if (t == 0) row_ptr[N_NODES] = N_EDGES;
}

__global__ __launch_bounds__(256)
void passC(const int* __restrict__ src, const int* __restrict__ dst,
           const int* __restrict__ blk_off_src, const int* __restrict__ blk_off_dst,
           const int* __restrict__ base_src, const int* __restrict__ base_dst,
           int* __restrict__ sorted_srconly, int* __restrict__ sorted_dst,
           int* __restrict__ sorted_srcpair) {
    __shared__ int cs[NBKT], cd[NBKT];
    const int t = threadIdx.x, blk = blockIdx.x;
    for (int b = t; b < NBKT; b += 256) {
        cs[b] = base_src[b] + blk_off_src[b * NBLK_E + blk];
        cd[b] = base_dst[b] + blk_off_dst[b * NBLK_E + blk];
    }
    __syncthreads();
    const int e0 = blk * EPB;
    const int e1 = (e0 + EPB < N_EDGES) ? e0 + EPB : N_EDGES;
    for (int e = e0 + t; e < e1; e += 256) {
        int sv = src[e], dv = dst[e];
        int ps = atomicAdd(&cs[sv >> BSHIFT], 1);
        sorted_srconly[ps] = sv;
        int pd = atomicAdd(&cd[dv >> BSHIFT], 1);
        sorted_dst[pd] = dv;
        sorted_srcpair[pd] = sv;
    }
}

__global__ __launch_bounds__(256)
void passDsrc(const int* __restrict__ base_src, const int* __restrict__ sorted_srconly,
              float* __restrict__ dis) {
    __shared__ int hist[128];
    const int b = blockIdx.x, t = threadIdx.x;
    if (t < 128) hist[t] = 0;
    __syncthreads();
    const int eb = base_src[b], ee = base_src[b + 1];
    for (int i = eb + t; i < ee; i += 256)
        atomicAdd(&hist[sorted_srconly[i] & 127], 1);
    __syncthreads();
    const int node = (b << BSHIFT) + t;
    if (t < 128 && node < N_NODES) {
        int c = hist[t];
        dis[node] = c > 0 ? rsqrtf((float)c) : 0.0f;
    }
}

__global__ __launch_bounds__(256)
void passDdst(const int* __restrict__ base_dst, const int* __restrict__ sorted_dst,
              const int* __restrict__ sorted_srcpair, const float* __restrict__ dis,
              int* __restrict__ row_ptr, int* __restrict__ wsrc, float* __restrict__ wval) {
    __shared__ int s_d[DCAP];
    __shared__ int s_s[DCAP];
    __shared__ int hist[128];
    __shared__ int cur[128];
    __shared__ float s_dis[128];
    const int b = blockIdx.x, t = threadIdx.x;
    if (t < 128) {
        hist[t] = 0;
        int node = (b << BSHIFT) + t;
        s_dis[t] = (node < N_NODES) ? dis[node] : 0.0f;
    }
    __syncthreads();
    const int eb = base_dst[b], ee = base_dst[b + 1];
    const int cnt = ee - eb;
    const int stage = cnt < DCAP ? cnt : DCAP;
    for (int i = t; i < stage; i += 256) {
        int d = sorted_dst[eb + i] & 127;
        s_d[i] = d;
        s_s[i] = sorted_srcpair[eb + i];
        atomicAdd(&hist[d], 1);
    }
    for (int i = stage + t; i < cnt; i += 256)
        atomicAdd(&hist[sorted_dst[eb + i] & 127], 1);
    __syncthreads();
    if (t < 64) {
        int v0 = hist[2 * t], v1 = hist[2 * t + 1];
        int p = v0 + v1;
        int incl = p;
        #pragma unroll
        for (int off = 1; off < 64; off <<= 1) {
            int x = __shfl_up(incl, off);
            if (t >= off) incl += x;
        }
        int excl = incl - p;
        cur[2 * t] = excl;
        cur[2 * t + 1] = excl + v0;
        int node = (b << BSHIFT) + 2 * t;
        if (node < N_NODES) row_ptr[node] = eb + excl;
        if (node + 1 < N_NODES) row_ptr[node + 1] = eb + excl + v0;
    }
    __syncthreads();
    for (int i = t; i < stage; i += 256) {
        int ln = s_d[i], sv = s_s[i];
        int slot = atomicAdd(&cur[ln], 1);
        wsrc[eb + slot] = sv;
        wval[eb + slot] = -dis[sv] * s_dis[ln];
    }
    for (int i = stage + t; i < cnt; i += 256) {
        int ln = sorted_dst[eb + i] & 127, sv = sorted_srcpair[eb + i];
        int slot = atomicAdd(&cur[ln], 1);
        wsrc[eb + slot] = sv;
        wval[eb + slot] = -dis[sv] * s_dis[ln];
    }
}

// ============ weight pack (both layers, MFMA B-fragment order) ============

__global__ void packB_both(const float* __restrict__ W1, const float* __restrict__ W2,
                           u16* __restrict__ Pb1, u16* __restrict__ Pb2) {
    int t = blockIdx.x * blockDim.x + threadIdx.x;
    if (t < 3 * D_IN * HID) {                    // 18432: K=96, NC=192, OUTW=64
        int j = t & 7, rest = t >> 3;
        int c = rest % 192, i = (rest / 192) * 8 + j;
        int kc = c / 64, o = c % 64;
        Pb1[t] = f2bf(W1[((long)kc * D_IN + i) * HID + o]);
    } else if (t < 3 * D_IN * HID + 3 * HID * D_OUT) {
        int t2 = t - 3 * D_IN * HID;             // 3072: K=64, NC=48, OUTW=16
        int j = t2 & 7, rest = t2 >> 3;
        int c = rest % 48, i = (rest / 48) * 8 + j;
        int kc = c / 16, o = c % 16;
        Pb2[t2] = f2bf(W2[((long)kc * HID + i) * D_OUT + o]);
    }
}

// ============ MFMA GEMM: Z = A[N,K] @ B[K,NC], plane-split output ============
// col c = ct*16+r16 stored at Z + (ct/CPK)*CBS + node*LDZ + (ct%CPK)*16 + r16

template<int K, int NC, int LDZ, int CPK, long CBS, bool AF32>
__global__ __launch_bounds__(256)
void gemm_mfma(const void* __restrict__ Av, const u16* __restrict__ P, u16* __restrict__ Z) {
    constexpr int KT = K / 32;
    constexpr int TOT = KT * 4 * NC * 8;
    __shared__ u16 sP[TOT];
    for (int idx = threadIdx.x * 8; idx < TOT; idx += 2048)
        *(uint4*)&sP[idx] = *(const uint4*)&P[idx];
    __syncthreads();
    const int lane = threadIdx.x & 63;
    const int tile = blockIdx.x * 4 + (threadIdx.x >> 6);
    if (tile * 16 >= N_NODES) return;
    const int node0 = tile * 16;
    const int sub = lane >> 4, r16 = lane & 15;
    bf16x8 a[KT];
    if (AF32) {
        const float* ar = (const float*)Av + (long)(node0 + r16) * K + sub * 8;
        #pragma unroll
        for (int kt = 0; kt < KT; ++kt) {
            float4 a0 = *(const float4*)(ar + kt * 32);
            float4 a1 = *(const float4*)(ar + kt * 32 + 4);
            union { bf16x8 v; uint4 q; } u;
            u.q.x = pack2(a0.x, a0.y); u.q.y = pack2(a0.z, a0.w);
            u.q.z = pack2(a1.x, a1.y); u.q.w = pack2(a1.z, a1.w);
            a[kt] = u.v;
        }
    } else {
        const u16* ar = (const u16*)Av + (long)(node0 + r16) * K + sub * 8;
        #pragma unroll
        for (int kt = 0; kt < KT; ++kt)
            a[kt] = *(const bf16x8*)(ar + kt * 32);
    }
    #pragma unroll
    for (int ct = 0; ct < NC / 16; ++ct) {
        f32x4 acc = {0.f, 0.f, 0.f, 0.f};
        #pragma unroll
        for (int kt = 0; kt < KT; ++kt) {
            bf16x8 bfr = *(const bf16x8*)&sP[((kt * 4 + sub) * NC + ct * 16 + r16) * 8];
            acc = __builtin_amdgcn_mfma_f32_16x16x32_bf16(a[kt], bfr, acc, 0, 0, 0);
        }
        u16* zp = Z + (long)(ct / CPK) * CBS + (long)(node0 + sub * 4) * LDZ + (ct % CPK) * 16 + r16;
        #pragma unroll
        for (int r = 0; r < 4; ++r)
            zp[(long)r * LDZ] = f2bf(acc[r]);
    }
}

// ============ gather propagate with fused Chebyshev epilogues ============
// EPI_S  : S   = aux1 + 2*acc                      (bf16 out)
// EPI_H  : h   = relu(aux1 - aux2 + acc + bias)    (bf16 out)
// EPI_OUT: out = aux1 - aux2 + acc + bias          (f32 out)

#define EPI_S 0
#define EPI_H 1
#define EPI_OUT 2

__device__ inline void accum8(float (&acc)[8], float we, uint4 q) {
    acc[0] = fmaf(we, bflo(q.x), acc[0]);
    acc[1] = fmaf(we, bfhi(q.x), acc[1]);
    acc[2] = fmaf(we, bflo(q.y), acc[2]);
    acc[3] = fmaf(we, bfhi(q.y), acc[3]);
    acc[4] = fmaf(we, bflo(q.z), acc[4]);
    acc[5] = fmaf(we, bfhi(q.z), acc[5]);
    acc[6] = fmaf(we, bflo(q.w), acc[6]);
    acc[7] = fmaf(we, bfhi(q.w), acc[7]);
}

template<int F, int NPB, int CAP, int EPI>
__global__ __launch_bounds__(256)
void gather_prop(const int* __restrict__ row_ptr, const int* __restrict__ wsrc,
                 const float* __restrict__ wval,
                 const u16* __restrict__ g,       // gather source plane [N,F]
                 const u16* __restrict__ aux1,
                 const u16* __restrict__ aux2,
                 const float* __restrict__ bias,
                 void* __restrict__ outp) {
    __shared__ int   s_src[CAP];
    __shared__ float s_w[CAP];
    __shared__ int   s_beg[NPB + 1];
    const int tid = threadIdx.x;
    const int node0 = blockIdx.x * NPB;
    if (tid <= NPB) {
        int n = node0 + tid;
        s_beg[tid] = row_ptr[n > N_NODES ? N_NODES : n];
    }
    __syncthreads();
    const int ebeg = s_beg[0];
    const int cnt = s_beg[NPB] - ebeg;
    const int stage = cnt < CAP ? cnt : CAP;
    for (int e = tid; e < stage; e += 256) {
        s_src[e] = wsrc[ebeg + e];
        s_w[e]   = wval[ebeg + e];
    }
    __syncthreads();
    const int CPN = F / 8;
    const int nl = tid / CPN;
    const int node = node0 + nl;
    if (nl >= NPB || node >= N_NODES) return;
    const int c8 = (tid % CPN) * 8;
    float acc[8];
    #pragma unroll
    for (int j = 0; j < 8; ++j) acc[j] = 0.0f;
    const int beg = s_beg[nl] - ebeg;
    const int end = s_beg[nl + 1] - ebeg;
    const int mid = end < stage ? end : stage;
    int e = beg;
    for (; e + 4 <= mid; e += 4) {                // 4-way MLP unroll
        const float w0 = s_w[e], w1 = s_w[e + 1], w2 = s_w[e + 2], w3 = s_w[e + 3];
        const uint4 q0 = *(const uint4*)(g + (long)s_src[e]     * F + c8);
        const uint4 q1 = *(const uint4*)(g + (long)s_src[e + 1] * F + c8);
        const uint4 q2 = *(const uint4*)(g + (long)s_src[e + 2] * F + c8);
        const uint4 q3 = *(const uint4*)(g + (long)s_src[e + 3] * F + c8);
        accum8(acc, w0, q0); accum8(acc, w1, q1);
        accum8(acc, w2, q2); accum8(acc, w3, q3);
    }
    for (; e < mid; ++e) {
        const float we = s_w[e];
        const uint4 q = *(const uint4*)(g + (long)s_src[e] * F + c8);
        accum8(acc, we, q);
    }
    for (e = (beg > stage ? beg : stage); e < end; ++e) {   // overflow fallback (rare)
        const float we = wval[ebeg + e];
        const uint4 q = *(const uint4*)(g + (long)wsrc[ebeg + e] * F + c8);
        accum8(acc, we, q);
    }
    if (EPI == EPI_S) {
        const uint4 z1 = *(const uint4*)(aux1 + (long)node * F + c8);
        uint4 r;
        r.x = pack2(bflo(z1.x) + 2.f * acc[0], bfhi(z1.x) + 2.f * acc[1]);
        r.y = pack2(bflo(z1.y) + 2.f * acc[2], bfhi(z1.y) + 2.f * acc[3]);
        r.z = pack2(bflo(z1.z) + 2.f * acc[4], bfhi(z1.z) + 2.f * acc[5]);
        r.w = pack2(bflo(z1.w) + 2.f * acc[6], bfhi(z1.w) + 2.f * acc[7]);
        *(uint4*)((u16*)outp + (long)node * F + c8) = r;
    } else {
        const uint4 z0 = *(const uint4*)(aux1 + (long)node * F + c8);
        const uint4 z2 = *(const uint4*)(aux2 + (long)node * F + c8);
        const float* bb = bias + c8;
        float v0 = bflo(z0.x) - bflo(z2.x) + acc[0] + bb[0];
        float v1 = bfhi(z0.x) - bfhi(z2.x) + acc[1] + bb[1];
        float v2 = bflo(z0.y) - bflo(z2.y) + acc[2] + bb[2];
        float v3 = bfhi(z0.y) - bfhi(z2.y) + acc[3] + bb[3];
        float v4 = bflo(z0.z) - bflo(z2.z) + acc[4] + bb[4];
        float v5 = bfhi(z0.z) - bfhi(z2.z) + acc[5] + bb[5];
        float v6 = bflo(z0.w) - bflo(z2.w) + acc[6] + bb[6];
        float v7 = bfhi(z0.w) - bfhi(z2.w) + acc[7] + bb[7];
        if (EPI == EPI_H) {
            uint4 r;
            r.x = pack2(fmaxf(v0, 0.f), fmaxf(v1, 0.f));
            r.y = pack2(fmaxf(v2, 0.f), fmaxf(v3, 0.f));
            r.z = pack2(fmaxf(v4, 0.f), fmaxf(v5, 0.f));
            r.w = pack2(fmaxf(v6, 0.f), fmaxf(v7, 0.f));
            *(uint4*)((u16*)outp + (long)node * F + c8) = r;
        } else {
            float* op = (float*)outp + (long)node * F + c8;
            *(float4*)op = make_float4(v0, v1, v2, v3);
            *(float4*)(op + 4) = make_float4(v4, v5, v6, v7);
        }
    }
}

// ============ launch ============

extern "C" void kernel_launch(void* const* d_in, const int* in_sizes, int n_in,
                              void* d_out, int out_size, void* d_ws, size_t ws_size,
                              hipStream_t stream) {
    const float* x  = (const float*)d_in[0];
    const int*   ei = (const int*)d_in[1];
    const float* W1 = (const float*)d_in[2];
    const float* b1 = (const float*)d_in[3];
    const float* W2 = (const float*)d_in[4];
    const float* b2 = (const float*)d_in[5];
    const int* src = ei;
    const int* dst = ei + N_EDGES;

    // ---- workspace (all sections 16B-aligned) ----
    float* dis          = (float*)d_ws;                      // 50000
    int*   row_ptr      = (int*)(dis + N_NODES);             // 50016
    int*   blk_cnt_src  = row_ptr + 50016;                   // 152896
    int*   blk_cnt_dst  = blk_cnt_src + 152896;              // 152896
    int*   tot_src      = blk_cnt_dst + 152896;              // 512
    int*   tot_dst      = tot_src + 512;                     // 512
    int*   base_src     = tot_dst + 512;                     // 512
    int*   base_dst     = base_src + 512;                    // 512
    int*   sorted_dst   = base_dst + 512;                    // E
    int*   sorted_srcp  = sorted_dst + N_EDGES;              // E
    int*   wsrc         = sorted_srcp + N_EDGES;             // E (aliases sorted_srconly)
    float* wval         = (float*)(wsrc + N_EDGES);          // E
    u16*   Pb1          = (u16*)(wval + N_EDGES);            // 18432
    u16*   Pb2          = Pb1 + 18432;                       // 3072
    u16*   Z            = Pb2 + 3072;                        // [3 planes][N][64]
    u16*   S            = Z + (long)3 * N_NODES * HID;       // N*64
    u16*   hb           = S + (long)N_NODES * HID;           // N*64
    u16*   Zp           = hb + (long)N_NODES * HID;          // [3 planes][N][16]
    u16*   Sp           = Zp + (long)3 * N_NODES * D_OUT;    // N*16
    int*   sorted_srconly = wsrc;                            // consumed before wsrc written

    const long PZ  = (long)N_NODES * HID;    // layer-1 plane stride
    const long PZp = (long)N_NODES * D_OUT;  // layer-2 plane stride

    // ---- CSR build (no global atomics) ----
    passA<<<NBLK_E, 256, 0, stream>>>(src, dst, blk_cnt_src, blk_cnt_dst);
    passB<<<2 * NBKT, 64, 0, stream>>>(blk_cnt_src, blk_cnt_dst, tot_src, tot_dst);
    passB2<<<1, 256, 0, stream>>>(tot_src, tot_dst, base_src, base_dst, row_ptr);
    passC<<<NBLK_E, 256, 0, stream>>>(src, dst, blk_cnt_src, blk_cnt_dst, base_src, base_dst,
                                      sorted_srconly, sorted_dst, sorted_srcp);
    passDsrc<<<NBKT, 256, 0, stream>>>(base_src, sorted_srconly, dis);
    passDdst<<<NBKT, 256, 0, stream>>>(base_dst, sorted_dst, sorted_srcp, dis,
                                       row_ptr, wsrc, wval);

    // ---- weights ----
    packB_both<<<(3 * D_IN * HID + 3 * HID * D_OUT + 255) / 256, 256, 0, stream>>>(W1, W2, Pb1, Pb2);

    // ---- layer 1: Z = x @ W1 (planes Z0|Z1|Z2), S = Z1 + 2 L Z2, h = relu(Z0 - Z2 + L S + b1) ----
    const int GB = (N_NODES / 16 + 3) / 4;   // 782
    gemm_mfma<D_IN, 192, HID, 4, (long)N_NODES * HID, true><<<GB, 256, 0, stream>>>(x, Pb1, Z);
    gather_prop<HID, 32, 1024, EPI_S><<<(N_NODES + 31) / 32, 256, 0, stream>>>(
        row_ptr, wsrc, wval, Z + 2 * PZ, Z + PZ, nullptr, nullptr, S);
    gather_prop<HID, 32, 1024, EPI_H><<<(N_NODES + 31) / 32, 256, 0, stream>>>(
        row_ptr, wsrc, wval, S, Z, Z + 2 * PZ, b1, hb);

    // ---- layer 2: Zp = h @ W2 (planes), Sp = Z'1 + 2 L Z'2, out = Z'0 - Z'2 + L Sp + b2 ----
    gemm_mfma<HID, 48, D_OUT, 1, (long)N_NODES * D_OUT, false><<<GB, 256, 0, stream>>>(hb, Pb2, Zp);
    gather_prop<D_OUT, 128, 3072, EPI_S><<<(N_NODES + 127) / 128, 256, 0, stream>>>(
        row_ptr, wsrc, wval, Zp + 2 * PZp, Zp + PZp, nullptr, nullptr, Sp);
    gather_prop<D_OUT, 128, 3072, EPI_OUT><<<(N_NODES + 127) / 128, 256, 0, stream>>>(
        row_ptr, wsrc, wval, Sp, Zp, Zp + 2 * PZp, b2, (float*)d_out);
}